// Round 9
// baseline (243.575 us; speedup 1.0000x reference)
//
#include <hip/hip_runtime.h>
#include <hip/hip_bf16.h>
#include <math.h>

#define B_ 2
#define T_ 2048
#define C_ 1024
#define H_ 16
#define G_ 4
#define DQK_ 64
#define DV_ 128
#define NQKV 1792   // H*DQK + G*DQK + G*DV
#define KS2 2048    // compact split storage: [hi | lo]
// Variable-K split GEMM: Q/K columns (n<1280) use 64 tiles
// (hi·hi 0..31, lo·hi 32..63); V columns (n>=1280) use 32 (hi·hi only).
// Operand rows chunk-XOR-swizzled: chunk c of row r at phys chunk c^((r>>1)&3).

typedef __attribute__((ext_vector_type(8))) short short8;
typedef __attribute__((ext_vector_type(4))) float f32x4;
typedef unsigned short ushort_t;

__device__ inline ushort_t f2bf(float f) {
  union { float f; unsigned int u; } v; v.f = f;
  unsigned int r = (v.u + 0x7FFFu + ((v.u >> 16) & 1u)) >> 16;  // RNE
  return (ushort_t)r;
}
__device__ inline float bf2f(ushort_t h) {
  union { unsigned int u; float f; } v; v.u = ((unsigned int)h) << 16;
  return v.f;
}
// single-instruction RNE f32->bf16 (dst.lo = cvt(src)); P is finite in (0,1]
__device__ inline ushort_t f2bf_hw(float f) {
  unsigned int u;
  asm("v_cvt_pk_bf16_f32 %0, %1, %1" : "=v"(u) : "v"(f));
  return (ushort_t)u;
}

#define GLD_LDS16(g, l)                                              \
  __builtin_amdgcn_global_load_lds(                                  \
      (const __attribute__((address_space(1))) void*)(g),            \
      (__attribute__((address_space(3))) void*)(l), 16, 0, 0)

// ---------------------------------------------------------------------------
// Kernel 0a: split-cast x -> xb[4096][2048] bf16 = [x_hi | x_lo], swizzled.
// ---------------------------------------------------------------------------
__global__ __launch_bounds__(256) void cast_x(
    const float* __restrict__ x, ushort_t* __restrict__ xb) {
  int idx = blockIdx.x * 256 + threadIdx.x;   // 524288
  int m = idx >> 7;
  int c8 = idx & 127;
  const float* src = &x[(size_t)m * 1024 + c8 * 8];
  float4 v0 = *(const float4*)&src[0];
  float4 v1 = *(const float4*)&src[4];
  float f[8] = {v0.x, v0.y, v0.z, v0.w, v1.x, v1.y, v1.z, v1.w};
  short8 hv, lv;
#pragma unroll
  for (int c = 0; c < 8; c++) {
    ushort_t h = f2bf(f[c]);
    hv[c] = (short)h;
    lv[c] = (short)f2bf(f[c] - bf2f(h));
  }
  int key = (m >> 1) & 3;
  int phys = (c8 & ~3) * 8 + ((c8 & 3) ^ key) * 8;
  ushort_t* row = xb + (size_t)m * KS2;
  *(short8*)&row[phys] = hv;
  *(short8*)&row[1024 + phys] = lv;
}

// ---------------------------------------------------------------------------
// Kernel 0b: transpose+cast W -> wt[1792][2048] bf16 (hi half only), swizzled.
// ---------------------------------------------------------------------------
__global__ __launch_bounds__(256) void cast_w(
    const float* __restrict__ Wq, const float* __restrict__ Wk,
    const float* __restrict__ Wv, ushort_t* __restrict__ wt) {
  __shared__ float tile[64][65];
  const int n0 = blockIdx.x * 64;
  const int k0 = blockIdx.y * 64;
  const int tid = threadIdx.x;

  const float* Wp; int ldw, noff;
  if (n0 < 1024)      { Wp = Wq; ldw = 1024; noff = n0; }
  else if (n0 < 1280) { Wp = Wk; ldw = 256;  noff = n0 - 1024; }
  else                { Wp = Wv; ldw = 512;  noff = n0 - 1280; }

#pragma unroll
  for (int it = 0; it < 4; it++) {
    int fi = it * 256 + tid;
    int kk = fi >> 4;
    int nc = (fi & 15) * 4;
    float4 v = *(const float4*)&Wp[(size_t)(k0 + kk) * ldw + noff + nc];
    tile[nc + 0][kk] = v.x; tile[nc + 1][kk] = v.y;
    tile[nc + 2][kk] = v.z; tile[nc + 3][kk] = v.w;
  }
  __syncthreads();
  int nn = tid >> 2, seg = tid & 3;
  int n = n0 + nn;
  int key = (n >> 1) & 3;
  ushort_t* row = wt + (size_t)n * KS2;
#pragma unroll
  for (int j = 0; j < 2; j++) {
    short8 hv;
#pragma unroll
    for (int u = 0; u < 8; u++)
      hv[u] = (short)f2bf(tile[nn][seg * 16 + j * 8 + u]);
    int c8 = (k0 >> 3) + seg * 2 + j;
    int phys = (c8 & ~3) * 8 + ((c8 & 3) ^ key) * 8;
    *(short8*)&row[phys] = hv;
  }
}

// ---------------------------------------------------------------------------
// Kernel 0c: cast Wproj[128][1024] -> bf16 B-fragment order.
// ---------------------------------------------------------------------------
__global__ __launch_bounds__(256) void cast_wp(
    const float* __restrict__ Wp, ushort_t* __restrict__ wpf) {
  int idx = blockIdx.x * 256 + threadIdx.x;   // 16384
  int n = idx & 1023;
  int kc = idx >> 10;                          // 0..15 (chunk of 8 k's)
  short8 v;
#pragma unroll
  for (int j = 0; j < 8; j++)
    v[j] = (short)f2bf(Wp[(size_t)(kc * 8 + j) * 1024 + n]);
  size_t off = (((size_t)(n >> 7) * 4 + (kc >> 2)) * 8 + ((n >> 4) & 7)) * 512 +
               ((kc & 3) * 16 + (n & 15)) * 8;
  *(short8*)&wpf[off] = v;
}

// ---------------------------------------------------------------------------
// Kernel 1: bf16-MFMA QKV GEMM.  2-barrier single-buffer K-loop +
// conflict-free swizzled LDS; variable K per column group (64 QK / 32 V).
// ---------------------------------------------------------------------------
__global__ __launch_bounds__(256) void gemm_qkv_mfma(
    const ushort_t* __restrict__ xb, const ushort_t* __restrict__ wt,
    float* __restrict__ qkv) {
  __shared__ ushort_t At[128 * 32];
  __shared__ ushort_t Bt[128 * 32];
  const int tid = threadIdx.x;
  const int wave = tid >> 6, lane = tid & 63;
  const int quad = lane >> 4, l16 = lane & 15;
  const int m0 = blockIdx.y * 128, n0 = blockIdx.x * 128;
  const int wm = (wave & 1) * 64, wn = (wave >> 1) * 64;
  const int physq = (quad ^ ((l16 >> 1) & 3)) * 8;   // de-swizzle read column
  const int ntiles = (n0 >= 1280) ? 32 : 64;

  f32x4 acc[4][4];
#pragma unroll
  for (int i = 0; i < 4; i++)
#pragma unroll
    for (int j = 0; j < 4; j++) acc[i][j] = (f32x4){0.f, 0.f, 0.f, 0.f};

  const int rA = wave * 32 + (lane >> 2);
  const int cA = (lane & 3) * 8;
  const ushort_t* gA = xb + (size_t)(m0 + rA) * KS2 + cA;
  const ushort_t* gB = wt + (size_t)(n0 + rA) * KS2 + cA;
  ushort_t* lA0 = At + (size_t)(wave * 32) * 32;
  ushort_t* lA1 = At + (size_t)(wave * 32 + 16) * 32;
  ushort_t* lB0 = Bt + (size_t)(wave * 32) * 32;
  ushort_t* lB1 = Bt + (size_t)(wave * 32 + 16) * 32;

  for (int kt = 0; kt < ntiles; kt++) {
    const int ca = kt * 32;
    const int cb = (kt < 32 ? kt : kt - 32) * 32;
    __syncthreads();
    GLD_LDS16(gA + ca, lA0);
    GLD_LDS16(gA + ca + 16 * KS2, lA1);
    GLD_LDS16(gB + cb, lB0);
    GLD_LDS16(gB + cb + 16 * KS2, lB1);
    __syncthreads();

    short8 af[4], bf[4];
#pragma unroll
    for (int i = 0; i < 4; i++)
      af[i] = *(const short8*)&At[(wm + 16 * i + l16) * 32 + physq];
#pragma unroll
    for (int j = 0; j < 4; j++)
      bf[j] = *(const short8*)&Bt[(wn + 16 * j + l16) * 32 + physq];
#pragma unroll
    for (int i = 0; i < 4; i++)
#pragma unroll
      for (int j = 0; j < 4; j++)
        acc[i][j] = __builtin_amdgcn_mfma_f32_16x16x32_bf16(
            af[i], bf[j], acc[i][j], 0, 0, 0);
  }

#pragma unroll
  for (int i = 0; i < 4; i++) {
    int m = m0 + wm + 16 * i + quad * 4;
#pragma unroll
    for (int j = 0; j < 4; j++) {
      int n = n0 + wn + 16 * j + l16;
#pragma unroll
      for (int r = 0; r < 4; r++)
        qkv[(size_t)(m + r) * NQKV + n] = acc[i][j][r];
    }
  }
}

// ---------------------------------------------------------------------------
// Kernel 2: RoPE + qk-norm -> unit-norm bf16 q,k in MFMA-fragment layouts.
// ---------------------------------------------------------------------------
__global__ __launch_bounds__(256) void rope_norm(
    const float* __restrict__ qkv,
    ushort_t* __restrict__ qf, ushort_t* __restrict__ kf) {
  const int NQ = B_ * T_ * H_;
  int vec = blockIdx.x * 4 + (threadIdx.x >> 6);
  int d = threadIdx.x & 63;

  size_t src; int t, b, isq; ushort_t* dstbase;
  if (vec < NQ) {
    int h = vec % H_; int bt = vec / H_;
    t = bt % T_; b = bt / T_;
    src = (size_t)bt * NQKV + h * 64 + d;
    dstbase = qf + (size_t)(b * 16 + h) * 131072;
    isq = 1;
  } else {
    int vk = vec - NQ;
    int g = vk % G_; int bt = vk / G_;
    t = bt % T_; b = bt / T_;
    src = (size_t)bt * NQKV + 1024 + g * 64 + d;
    dstbase = kf + (size_t)(b * 4 + g) * 131072;
    isq = 0;
  }
  float val = qkv[src];
  int i = d & 31;
  float inv = exp2f(-(float)i * 0.4152410118074239f);  // log2(10000)/32
  float ang = (float)t * inv;
  float sn, cs;
  __sincosf(ang, &sn, &cs);
  float partner = __shfl(val, d ^ 32, 64);
  float r = (d < 32) ? (val * cs - partner * sn) : (val * cs + partner * sn);
  float ss = r * r;
#pragma unroll
  for (int off = 32; off; off >>= 1) ss += __shfl_xor(ss, off, 64);
  r *= 1.0f / (sqrtf(ss) + 1e-6f);

  int kt = t >> 6, tt = t & 63;
  int l16v = tt & 15;
  int ks = d >> 5, quad = (d >> 3) & 3, j = d & 7;
  size_t off2;
  if (isq) {
    int wavei = tt >> 4;
    off2 = ((size_t)(kt * 8 + wavei * 2 + ks) * 4 + quad) * 128 + l16v * 8 + j;
  } else {
    int nt = tt >> 4;
    off2 = ((size_t)(kt * 8 + ks * 4 + nt) * 4 + quad) * 128 + l16v * 8 + j;
  }
  dstbase[off2] = f2bf(r);
}

// ---------------------------------------------------------------------------
// Kernel 2b: V scatter + bf16 cast into PV B-fragment layout.
// ---------------------------------------------------------------------------
__global__ __launch_bounds__(256) void vscatter(
    const float* __restrict__ qkv, ushort_t* __restrict__ vf) {
  int idx = blockIdx.x * 256 + threadIdx.x;   // 2,097,152
  int dv = idx & 127;
  int t = (idx >> 7) & 2047;
  int g = (idx >> 18) & 3;
  int b = idx >> 20;
  size_t src = (size_t)(b * T_ + t) * NQKV + 1280 + g * 128 + dv;
  float v = qkv[src];
  int kt = t >> 6, ks = (t >> 5) & 1, quad = (t >> 3) & 3, j = t & 7;
  int nv = dv >> 4, l16v = dv & 15;
  size_t off = ((size_t)(kt * 16 + ks * 8 + nv) * 4 + quad) * 128 + l16v * 8 + j;
  vf[(size_t)(b * 4 + g) * 262144 + off] = f2bf(v);
}

// ---------------------------------------------------------------------------
// Kernel 3: bf16-MFMA causal flash attention, fixed-max softmax (m = gsc).
// ROUND 9: split-phase staging — K double-buffered, V latency-hidden.
//  - Round 8 diagnosis: both barriers bracket ONLY the GLD issue, so every
//    wave eats the full L2 staging latency every iteration; concurrency
//    decays 4->1 (exact-capacity grid, no backfill) -> avg ~2 blocks.
//  - Fix: K dbuf (2x8KB): K(kt+1) issued at iter top into the spare K
//    buffer; QK reads the resident one -> QK never waits on staging.
//    V single-buffered: V(kt) issued at iter top, consumed only AFTER the
//    mid-barrier, which lands after QK+exp (~800cy) -> V latency hidden.
//    mid-barrier = V visibility (pre-covered); end-barrier = read/overwrite
//    ordering (nothing pending).  Neither barrier sits on raw L2 latency.
//  - LDS 40.5KB -> 3 blocks/CU; grid 1024 > 768 capacity -> LPT backfill
//    queue keeps concurrency ~3 (tq = 31-slot, longest first).
//  - (256,3) ~170-reg cap; live state ~100 regs.  VALU trims retained.
// ---------------------------------------------------------------------------
__global__ __launch_bounds__(256, 3) void attn(
    const ushort_t* __restrict__ qf, const ushort_t* __restrict__ kf,
    const ushort_t* __restrict__ vf, const float* __restrict__ lobo,
    const float* __restrict__ qknf, float* __restrict__ y) {
  const int f = blockIdx.x;            // 1024 blocks
  const int bh = f & 31;
  const int slot = f >> 5;             // 0..31
  const int tq = 31 - slot;            // LPT: longest blocks first
  const int b = bh >> 4;
  const int h = bh & 15;
  const int g = h >> 2;

  __shared__ ushort_t Kb[2][4096];     // dbuf K: 8 rows x 512
  __shared__ ushort_t Vb[8192];        // V: 16 rows x 512
  __shared__ ushort_t Ps[4 * 1088];    // per-wave 16 rows x 68

  const int tid = threadIdx.x;
  const int wave = tid >> 6, lane = tid & 63;
  const int quad = lane >> 4, l16 = lane & 15;
  ushort_t* PsW = &Ps[wave * 1088];

  short8 bones;
  {
    short bv = (l16 == 0) ? (short)0x3F80 : (short)0;
#pragma unroll
    for (int j = 0; j < 8; j++) bones[j] = bv;
  }

  const ushort_t* qbase = qf + (size_t)(b * 16 + h) * 131072 + lane * 8;
  short8 aq0 = *(const short8*)&qbase[(size_t)(tq * 8 + wave * 2 + 0) * 512];
  short8 aq1 = *(const short8*)&qbase[(size_t)(tq * 8 + wave * 2 + 1) * 512];

  f32x4 o[9];
#pragma unroll
  for (int nv = 0; nv < 9; nv++) o[nv] = (f32x4){0.f, 0.f, 0.f, 0.f};

  const float gsc = qknf[0];
  const float sinkp = __expf(lobo[h] - gsc);

  const int row = tq * 64 + wave * 16 + quad * 4;   // +r

  // per-lane global pointers for staging (lane*8 element offset built in)
  const ushort_t* kgl = kf + (size_t)(b * 4 + g) * 131072 + lane * 8;
  const ushort_t* vgl = vf + (size_t)(b * 4 + g) * 262144 + lane * 8;

  // ---- prologue: stage K(0) into Kb[0] ----
  GLD_LDS16(kgl + (wave * 2 + 0) * 512, &Kb[0][(wave * 2 + 0) * 512]);
  GLD_LDS16(kgl + (wave * 2 + 1) * 512, &Kb[0][(wave * 2 + 1) * 512]);
  __syncthreads();   // K(0) landed (vmcnt drained by barrier)

  for (int kt = 0; kt <= tq; kt++) {
    // ---- issue V(kt) into Vb; K(kt+1) into the spare K buffer ----
    {
      const ushort_t* gv = vgl + (size_t)kt * 8192;
#pragma unroll
      for (int j = 0; j < 4; j++)
        GLD_LDS16(gv + (wave * 4 + j) * 512, &Vb[(wave * 4 + j) * 512]);
      if (kt < tq) {
        const ushort_t* gk = kgl + (size_t)(kt + 1) * 4096;
        ushort_t* kd = &Kb[(kt + 1) & 1][0];
        GLD_LDS16(gk + (wave * 2 + 0) * 512, &kd[(wave * 2 + 0) * 512]);
        GLD_LDS16(gk + (wave * 2 + 1) * 512, &kd[(wave * 2 + 1) * 512]);
      }
    }

    // ---- QK from the RESIDENT K buffer (no staging wait) ----
    const ushort_t* Kc = &Kb[kt & 1][0];
    f32x4 s[4];
#pragma unroll
    for (int nt = 0; nt < 4; nt++) s[nt] = (f32x4){0.f, 0.f, 0.f, 0.f};
    {
      short8 kb[4];
#pragma unroll
      for (int u = 0; u < 4; u++)
        kb[u] = *(const short8*)&Kc[u * 512 + lane * 8];
      __builtin_amdgcn_s_setprio(1);
#pragma unroll
      for (int nt = 0; nt < 4; nt++)
        s[nt] = __builtin_amdgcn_mfma_f32_16x16x32_bf16(aq0, kb[nt], s[nt], 0, 0, 0);
      __builtin_amdgcn_s_setprio(0);
#pragma unroll
      for (int u = 0; u < 4; u++)
        kb[u] = *(const short8*)&Kc[(4 + u) * 512 + lane * 8];
      __builtin_amdgcn_s_setprio(1);
#pragma unroll
      for (int nt = 0; nt < 4; nt++)
        s[nt] = __builtin_amdgcn_mfma_f32_16x16x32_bf16(aq1, kb[nt], s[nt], 0, 0, 0);
      __builtin_amdgcn_s_setprio(0);
    }

    // ---- mask + exp + bf16 store; causal cmp only on diagonal iter ----
    if (kt == tq) {
#pragma unroll
      for (int nt = 0; nt < 4; nt++) {
        int key = kt * 64 + l16 + nt * 16;
#pragma unroll
        for (int r = 0; r < 4; r++) {
          float pv = (key <= row + r) ? __expf(fmaf(s[nt][r], gsc, -gsc)) : 0.f;
          PsW[(quad * 4 + r) * 68 + nt * 16 + l16] = f2bf_hw(pv);
        }
      }
    } else {
#pragma unroll
      for (int nt = 0; nt < 4; nt++)
#pragma unroll
        for (int r = 0; r < 4; r++)
          PsW[(quad * 4 + r) * 68 + nt * 16 + l16] =
              f2bf_hw(__expf(fmaf(s[nt][r], gsc, -gsc)));
    }

    // ---- mid-barrier: V(kt)/K(kt+1) landed (latency covered by QK+exp) ----
    __syncthreads();

    // ---- read P fragments, PV with V frags from LDS (4 batches of 4) ----
    short8 ap0 = *(const short8*)&PsW[l16 * 68 + quad * 8];
    short8 ap1 = *(const short8*)&PsW[l16 * 68 + 32 + quad * 8];
    {
      short8 vb[4];
#pragma unroll
      for (int u = 0; u < 4; u++)
        vb[u] = *(const short8*)&Vb[u * 512 + lane * 8];
      __builtin_amdgcn_s_setprio(1);
#pragma unroll
      for (int nv = 0; nv < 4; nv++)
        o[nv] = __builtin_amdgcn_mfma_f32_16x16x32_bf16(ap0, vb[nv], o[nv], 0, 0, 0);
      __builtin_amdgcn_s_setprio(0);
#pragma unroll
      for (int u = 0; u < 4; u++)
        vb[u] = *(const short8*)&Vb[(4 + u) * 512 + lane * 8];
      __builtin_amdgcn_s_setprio(1);
#pragma unroll
      for (int nv = 0; nv < 4; nv++)
        o[4 + nv] = __builtin_amdgcn_mfma_f32_16x16x32_bf16(ap0, vb[nv], o[4 + nv], 0, 0, 0);
      o[8] = __builtin_amdgcn_mfma_f32_16x16x32_bf16(ap0, bones, o[8], 0, 0, 0);
      o[8] = __builtin_amdgcn_mfma_f32_16x16x32_bf16(ap1, bones, o[8], 0, 0, 0);
      __builtin_amdgcn_s_setprio(0);
#pragma unroll
      for (int u = 0; u < 4; u++)
        vb[u] = *(const short8*)&Vb[(8 + u) * 512 + lane * 8];
      __builtin_amdgcn_s_setprio(1);
#pragma unroll
      for (int nv = 0; nv < 4; nv++)
        o[nv] = __builtin_amdgcn_mfma_f32_16x16x32_bf16(ap1, vb[nv], o[nv], 0, 0, 0);
      __builtin_amdgcn_s_setprio(0);
#pragma unroll
      for (int u = 0; u < 4; u++)
        vb[u] = *(const short8*)&Vb[(12 + u) * 512 + lane * 8];
      __builtin_amdgcn_s_setprio(1);
#pragma unroll
      for (int nv = 0; nv < 4; nv++)
        o[4 + nv] = __builtin_amdgcn_mfma_f32_16x16x32_bf16(ap1, vb[nv], o[4 + nv], 0, 0, 0);
      __builtin_amdgcn_s_setprio(0);
    }

    // ---- end-barrier: V reads done before next iter's overwrite ----
    __syncthreads();
  }

  // epilogue: l = sink + mfma row-sum (col 0 of o[8]); normalize; head-sum
#pragma unroll
  for (int r = 0; r < 4; r++) {
    float lm = __shfl(o[8][r], lane & 48, 64);
    float invl = 1.0f / (lm + sinkp);
    size_t gRow = (size_t)b * T_ + row + r;
#pragma unroll
    for (int nv = 0; nv < 8; nv++)
      atomicAdd(&y[gRow * 128 + nv * 16 + l16], o[nv][r] * invl);
  }
}

// ---------------------------------------------------------------------------
// Kernel 4: out = y[4096][128] @ Wproj[128][1024] via bf16 MFMA.
// ---------------------------------------------------------------------------
__global__ __launch_bounds__(256) void out_proj(
    const float* __restrict__ y, const ushort_t* __restrict__ wpf,
    float* __restrict__ out) {
  __shared__ ushort_t yl[128 * 136];
  const int tid = threadIdx.x;
  const int wave = tid >> 6, lane = tid & 63;
  const int quad = lane >> 4, l16 = lane & 15;
  const int n0 = blockIdx.x * 128, m0 = blockIdx.y * 128;
  const int wm = (wave & 1) * 64, wn = (wave >> 1) * 64;

#pragma unroll
  for (int it = 0; it < 8; it++) {
    int p = it * 256 + tid;
    int row = p >> 4, c8 = p & 15;
    const float* src = &y[(size_t)(m0 + row) * 128 + c8 * 8];
    float4 v0 = *(const float4*)&src[0];
    float4 v1 = *(const float4*)&src[4];
    float fv[8] = {v0.x, v0.y, v0.z, v0.w, v1.x, v1.y, v1.z, v1.w};
    short8 hv;
#pragma unroll
    for (int c = 0; c < 8; c++) hv[c] = (short)f2bf(fv[c]);
    *(short8*)&yl[row * 136 + c8 * 8] = hv;
  }
  __syncthreads();

  f32x4 acc[4][4];
#pragma unroll
  for (int i = 0; i < 4; i++)
#pragma unroll
    for (int j = 0; j < 4; j++) acc[i][j] = (f32x4){0.f, 0.f, 0.f, 0.f};

#pragma unroll
  for (int ks = 0; ks < 4; ks++) {
    short8 af[4], bfr[4];
#pragma unroll
    for (int i = 0; i < 4; i++)
      af[i] = *(const short8*)&yl[(wm + 16 * i + l16) * 136 + (ks * 4 + quad) * 8];
    const ushort_t* wb = wpf + (((size_t)(n0 >> 7) * 4 + ks) * 8) * 512;
#pragma unroll
    for (int j = 0; j < 4; j++)
      bfr[j] = *(const short8*)&wb[((size_t)((wn >> 4) + j)) * 512 + lane * 8];
#pragma unroll
    for (int i = 0; i < 4; i++)
#pragma unroll
      for (int j = 0; j < 4; j++)
        acc[i][j] = __builtin_amdgcn_mfma_f32_16x16x32_bf16(
            af[i], bfr[j], acc[i][j], 0, 0, 0);
  }

#pragma unroll
  for (int i = 0; i < 4; i++) {
    int m = m0 + wm + 16 * i + quad * 4;
#pragma unroll
    for (int j = 0; j < 4; j++) {
      int n = n0 + wn + 16 * j + l16;
#pragma unroll
      for (int r = 0; r < 4; r++)
        out[(size_t)(m + r) * 1024 + n] = acc[i][j][r];
    }
  }
}

// ---------------------------------------------------------------------------
extern "C" void kernel_launch(void* const* d_in, const int* in_sizes, int n_in,
                              void* d_out, int out_size, void* d_ws, size_t ws_size,
                              hipStream_t stream) {
  const float* x     = (const float*)d_in[0];
  const float* Wq    = (const float*)d_in[2];
  const float* Wk    = (const float*)d_in[3];
  const float* Wv    = (const float*)d_in[4];
  const float* Wproj = (const float*)d_in[5];
  const float* lobo  = (const float*)d_in[6];
  const float* qknf  = (const float*)d_in[7];
  float* out = (float*)d_out;

  // ws: [qkv f32 29.4MB | xb 16.8MB | wt 7.3MB | wpf 0.25MB]; qf/kf/vf/y alias xb.
  float* qkv = (float*)d_ws;                                    // 7,340,032 f32
  ushort_t* xb = (ushort_t*)(qkv + (size_t)B_ * T_ * NQKV);     // 8,388,608 bf16
  ushort_t* wt = xb + (size_t)B_ * T_ * KS2;                    // 3,670,016 bf16
  ushort_t* wpf = wt + (size_t)NQKV * KS2;                      //   131,072 bf16
  ushort_t* qf = xb;                                            // 4,194,304 bf16
  ushort_t* kf = qf + (size_t)B_ * H_ * T_ * 64;                // 1,048,576 bf16
  ushort_t* vf = kf + (size_t)B_ * G_ * T_ * 64;                // 2,097,152 bf16
  float* y = (float*)(vf + (size_t)B_ * G_ * T_ * 128);         //   524,288 f32

  cast_x<<<(B_ * T_ * 128) / 256, 256, 0, stream>>>(x, xb);
  dim3 gw(NQKV / 64, C_ / 64);
  cast_w<<<gw, 256, 0, stream>>>(Wq, Wk, Wv, wt);
  cast_wp<<<64, 256, 0, stream>>>(Wproj, wpf);

  dim3 gg(NQKV / 128, (B_ * T_) / 128);
  gemm_qkv_mfma<<<gg, 256, 0, stream>>>(xb, wt, qkv);

  int nvec = B_ * T_ * H_ + B_ * T_ * G_;   // 81920
  rope_norm<<<nvec / 4, 256, 0, stream>>>(qkv, qf, kf);

  vscatter<<<(B_ * G_ * T_ * DV_) / 256, 256, 0, stream>>>(qkv, vf);

  (void)hipMemsetAsync(y, 0, (size_t)B_ * T_ * 128 * sizeof(float), stream);

  attn<<<B_ * H_ * 32, 256, 0, stream>>>(qf, kf, vf, lobo, qknf, y);

  dim3 go(8, 32);
  out_proj<<<go, 256, 0, stream>>>(y, wpf, out);
}

// Round 10
// 216.274 us; speedup vs baseline: 1.1262x; 1.1262x over previous
//
#include <hip/hip_runtime.h>
#include <hip/hip_bf16.h>
#include <math.h>

#define B_ 2
#define T_ 2048
#define C_ 1024
#define H_ 16
#define G_ 4
#define DQK_ 64
#define DV_ 128
#define NQKV 1792   // H*DQK + G*DQK + G*DV
#define KS2 2048    // compact split storage: [hi | lo]
// Variable-K split GEMM: Q/K columns (n<1280) use 2048 K-depth
// (hi·hi + lo·hi); V columns (n>=1280) use 1024 (hi·hi only).
// Operand rows chunk-XOR-swizzled: chunk c of row r at phys chunk c^((r>>1)&3).

typedef __attribute__((ext_vector_type(8))) short short8;
typedef __attribute__((ext_vector_type(4))) float f32x4;
typedef unsigned short ushort_t;

__device__ inline ushort_t f2bf(float f) {
  union { float f; unsigned int u; } v; v.f = f;
  unsigned int r = (v.u + 0x7FFFu + ((v.u >> 16) & 1u)) >> 16;  // RNE
  return (ushort_t)r;
}
__device__ inline float bf2f(ushort_t h) {
  union { unsigned int u; float f; } v; v.u = ((unsigned int)h) << 16;
  return v.f;
}
// single-instruction RNE f32->bf16 (dst.lo = cvt(src)); P is finite in (0,1]
__device__ inline ushort_t f2bf_hw(float f) {
  unsigned int u;
  asm("v_cvt_pk_bf16_f32 %0, %1, %1" : "=v"(u) : "v"(f));
  return (ushort_t)u;
}

#define GLD_LDS16(g, l)                                              \
  __builtin_amdgcn_global_load_lds(                                  \
      (const __attribute__((address_space(1))) void*)(g),            \
      (__attribute__((address_space(3))) void*)(l), 16, 0, 0)

// ---------------------------------------------------------------------------
// Kernel 0 (FUSED): prep = cast_x | cast_w | cast_wp by blockIdx range.
//  blocks [0,2048): split-cast x -> xb[4096][2048] bf16 [hi|lo], swizzled.
//  blocks [2048,2496): transpose+cast W -> wt[1792][2048] (hi only), swizzled.
//  blocks [2496,2560): cast Wproj -> bf16 B-fragment order.
// Fusion cuts 2 kernel launches (launch-gap overhead was ~45% of total).
// ---------------------------------------------------------------------------
__global__ __launch_bounds__(256) void prep(
    const float* __restrict__ x, const float* __restrict__ Wq,
    const float* __restrict__ Wk, const float* __restrict__ Wv,
    const float* __restrict__ Wproj, ushort_t* __restrict__ xb,
    ushort_t* __restrict__ wt, ushort_t* __restrict__ wpf) {
  __shared__ float tile[64][65];
  const int bid = blockIdx.x;
  const int tid = threadIdx.x;

  if (bid < 2048) {
    // ---- cast_x ----
    int idx = bid * 256 + tid;   // 524288
    int m = idx >> 7;
    int c8 = idx & 127;
    const float* src = &x[(size_t)m * 1024 + c8 * 8];
    float4 v0 = *(const float4*)&src[0];
    float4 v1 = *(const float4*)&src[4];
    float f[8] = {v0.x, v0.y, v0.z, v0.w, v1.x, v1.y, v1.z, v1.w};
    short8 hv, lv;
#pragma unroll
    for (int c = 0; c < 8; c++) {
      ushort_t h = f2bf(f[c]);
      hv[c] = (short)h;
      lv[c] = (short)f2bf(f[c] - bf2f(h));
    }
    int key = (m >> 1) & 3;
    int phys = (c8 & ~3) * 8 + ((c8 & 3) ^ key) * 8;
    ushort_t* row = xb + (size_t)m * KS2;
    *(short8*)&row[phys] = hv;
    *(short8*)&row[1024 + phys] = lv;
  } else if (bid < 2496) {
    // ---- cast_w ----
    const int wid = bid - 2048;          // 0..447 = 28 x 16
    const int n0 = (wid % 28) * 64;
    const int k0 = (wid / 28) * 64;

    const float* Wp; int ldw, noff;
    if (n0 < 1024)      { Wp = Wq; ldw = 1024; noff = n0; }
    else if (n0 < 1280) { Wp = Wk; ldw = 256;  noff = n0 - 1024; }
    else                { Wp = Wv; ldw = 512;  noff = n0 - 1280; }

#pragma unroll
    for (int it = 0; it < 4; it++) {
      int fi = it * 256 + tid;
      int kk = fi >> 4;
      int nc = (fi & 15) * 4;
      float4 v = *(const float4*)&Wp[(size_t)(k0 + kk) * ldw + noff + nc];
      tile[nc + 0][kk] = v.x; tile[nc + 1][kk] = v.y;
      tile[nc + 2][kk] = v.z; tile[nc + 3][kk] = v.w;
    }
    __syncthreads();
    int nn = tid >> 2, seg = tid & 3;
    int n = n0 + nn;
    int key = (n >> 1) & 3;
    ushort_t* row = wt + (size_t)n * KS2;
#pragma unroll
    for (int j = 0; j < 2; j++) {
      short8 hv;
#pragma unroll
      for (int u = 0; u < 8; u++)
        hv[u] = (short)f2bf(tile[nn][seg * 16 + j * 8 + u]);
      int c8 = (k0 >> 3) + seg * 2 + j;
      int phys = (c8 & ~3) * 8 + ((c8 & 3) ^ key) * 8;
      *(short8*)&row[phys] = hv;
    }
  } else {
    // ---- cast_wp ----
    int idx = (bid - 2496) * 256 + tid;  // 16384
    int n = idx & 1023;
    int kc = idx >> 10;                  // 0..15 (chunk of 8 k's)
    short8 v;
#pragma unroll
    for (int j = 0; j < 8; j++)
      v[j] = (short)f2bf(Wproj[(size_t)(kc * 8 + j) * 1024 + n]);
    size_t off = (((size_t)(n >> 7) * 4 + (kc >> 2)) * 8 + ((n >> 4) & 7)) * 512 +
                 ((kc & 3) * 16 + (n & 15)) * 8;
    *(short8*)&wpf[off] = v;
  }
}

// ---------------------------------------------------------------------------
// Kernel 1: bf16-MFMA QKV GEMM.  ROUND 10: BK 32->64.
//  - The per-kt barrier pair exposes ~400-500cy of staging latency (the
//    m97-structure stall); BK=64 halves the barrier count and doubles the
//    MFMA per stage (32 vs 16) -> stall amortization 2x.
//  - LDS 2x16KB = 32KB (>=3 blocks/CU, unlike m132's 64KB regression).
//  - Chunk-XOR de-swizzle generalizes: sub-k s reads offset
//    s*32 + (quad^key)*8 within the 64-col row (key = (l16>>1)&3).
// ---------------------------------------------------------------------------
__global__ __launch_bounds__(256) void gemm_qkv_mfma(
    const ushort_t* __restrict__ xb, const ushort_t* __restrict__ wt,
    float* __restrict__ qkv) {
  __shared__ ushort_t At[128 * 64];
  __shared__ ushort_t Bt[128 * 64];
  const int tid = threadIdx.x;
  const int wave = tid >> 6, lane = tid & 63;
  const int quad = lane >> 4, l16 = lane & 15;
  const int m0 = blockIdx.y * 128, n0 = blockIdx.x * 128;
  const int wm = (wave & 1) * 64, wn = (wave >> 1) * 64;
  const int key = (l16 >> 1) & 3;
  const int ntiles = (n0 >= 1280) ? 16 : 32;

  f32x4 acc[4][4];
#pragma unroll
  for (int i = 0; i < 4; i++)
#pragma unroll
    for (int j = 0; j < 4; j++) acc[i][j] = (f32x4){0.f, 0.f, 0.f, 0.f};

  // staging: each GLD_LDS16 moves 64 lanes x 16B = 8 rows x 64 cols (1KB)
  const int rA = wave * 32 + (lane >> 3);
  const int cA = (lane & 7) * 8;
  const ushort_t* gA = xb + (size_t)(m0 + rA) * KS2 + cA;
  const ushort_t* gB = wt + (size_t)(n0 + rA) * KS2 + cA;

  for (int kt = 0; kt < ntiles; kt++) {
    const int ca = kt * 64;                         // A walks hi then lo
    const int cb = (kt < 16 ? kt : kt - 16) * 64;   // B wraps within hi
    __syncthreads();
#pragma unroll
    for (int j = 0; j < 4; j++) {
      GLD_LDS16(gA + ca + (size_t)(8 * j) * KS2, &At[(wave * 32 + 8 * j) * 64]);
      GLD_LDS16(gB + cb + (size_t)(8 * j) * KS2, &Bt[(wave * 32 + 8 * j) * 64]);
    }
    __syncthreads();

#pragma unroll
    for (int s = 0; s < 2; s++) {
      const int off = s * 32 + ((quad ^ key) * 8);
      short8 af[4], bf[4];
#pragma unroll
      for (int i = 0; i < 4; i++)
        af[i] = *(const short8*)&At[(wm + 16 * i + l16) * 64 + off];
#pragma unroll
      for (int j = 0; j < 4; j++)
        bf[j] = *(const short8*)&Bt[(wn + 16 * j + l16) * 64 + off];
#pragma unroll
      for (int i = 0; i < 4; i++)
#pragma unroll
        for (int j = 0; j < 4; j++)
          acc[i][j] = __builtin_amdgcn_mfma_f32_16x16x32_bf16(
              af[i], bf[j], acc[i][j], 0, 0, 0);
    }
  }

#pragma unroll
  for (int i = 0; i < 4; i++) {
    int m = m0 + wm + 16 * i + quad * 4;
#pragma unroll
    for (int j = 0; j < 4; j++) {
      int n = n0 + wn + 16 * j + l16;
#pragma unroll
      for (int r = 0; r < 4; r++)
        qkv[(size_t)(m + r) * NQKV + n] = acc[i][j][r];
    }
  }
}

// ---------------------------------------------------------------------------
// Kernel 2 (FUSED): rope_scatter = rope_norm | vscatter | y-zero by range.
//  blocks [0,20480): RoPE + qk-norm -> bf16 q,k fragment layouts.
//  blocks [20480,28672): V scatter + cast into PV B-fragment layout.
//  blocks [28672,29184): zero y (replaces hipMemsetAsync dispatch).
// ---------------------------------------------------------------------------
__global__ __launch_bounds__(256) void rope_scatter(
    const float* __restrict__ qkv, ushort_t* __restrict__ qf,
    ushort_t* __restrict__ kf, ushort_t* __restrict__ vf,
    float* __restrict__ y) {
  const int bid = blockIdx.x;
  const int tid = threadIdx.x;

  if (bid < 20480) {
    // ---- rope_norm ----
    const int NQ = B_ * T_ * H_;
    int vec = bid * 4 + (tid >> 6);
    int d = tid & 63;

    size_t src; int t, b, isq; ushort_t* dstbase;
    if (vec < NQ) {
      int h = vec % H_; int bt = vec / H_;
      t = bt % T_; b = bt / T_;
      src = (size_t)bt * NQKV + h * 64 + d;
      dstbase = qf + (size_t)(b * 16 + h) * 131072;
      isq = 1;
    } else {
      int vk = vec - NQ;
      int g = vk % G_; int bt = vk / G_;
      t = bt % T_; b = bt / T_;
      src = (size_t)bt * NQKV + 1024 + g * 64 + d;
      dstbase = kf + (size_t)(b * 4 + g) * 131072;
      isq = 0;
    }
    float val = qkv[src];
    int i = d & 31;
    float inv = exp2f(-(float)i * 0.4152410118074239f);  // log2(10000)/32
    float ang = (float)t * inv;
    float sn, cs;
    __sincosf(ang, &sn, &cs);
    float partner = __shfl(val, d ^ 32, 64);
    float r = (d < 32) ? (val * cs - partner * sn) : (val * cs + partner * sn);
    float ss = r * r;
#pragma unroll
    for (int off = 32; off; off >>= 1) ss += __shfl_xor(ss, off, 64);
    r *= 1.0f / (sqrtf(ss) + 1e-6f);

    int kt = t >> 6, tt = t & 63;
    int l16v = tt & 15;
    int ks = d >> 5, quad = (d >> 3) & 3, j = d & 7;
    size_t off2;
    if (isq) {
      int wavei = tt >> 4;
      off2 = ((size_t)(kt * 8 + wavei * 2 + ks) * 4 + quad) * 128 + l16v * 8 + j;
    } else {
      int nt = tt >> 4;
      off2 = ((size_t)(kt * 8 + ks * 4 + nt) * 4 + quad) * 128 + l16v * 8 + j;
    }
    dstbase[off2] = f2bf(r);
  } else if (bid < 28672) {
    // ---- vscatter ----
    int idx = (bid - 20480) * 256 + tid;   // 2,097,152
    int dv = idx & 127;
    int t = (idx >> 7) & 2047;
    int g = (idx >> 18) & 3;
    int b = idx >> 20;
    size_t src = (size_t)(b * T_ + t) * NQKV + 1280 + g * 128 + dv;
    float v = qkv[src];
    int kt = t >> 6, ks = (t >> 5) & 1, quad = (t >> 3) & 3, j = t & 7;
    int nv = dv >> 4, l16v = dv & 15;
    size_t off = ((size_t)(kt * 16 + ks * 8 + nv) * 4 + quad) * 128 + l16v * 8 + j;
    vf[(size_t)(b * 4 + g) * 262144 + off] = f2bf(v);
  } else {
    // ---- zero y ----
    int idx = (bid - 28672) * 256 + tid;   // 131072 float4s
    *(float4*)&y[(size_t)idx * 4] = (float4){0.f, 0.f, 0.f, 0.f};
  }
}

// ---------------------------------------------------------------------------
// Kernel 3: bf16-MFMA causal flash attention (ROUND-8 BODY — best: 67.5us).
// Single-buffer K/V LDS staging (2 barriers wrap staging only), 4 blocks/CU
// declared, serpentine balanced slot map, v_cvt_pk f2bf + fma exp arg.
// Round 9's split-phase staging regressed (mid-barrier drains the K
// prefetch vmcnt too) — reverted.
// ---------------------------------------------------------------------------
__global__ __launch_bounds__(256, 4) void attn(
    const ushort_t* __restrict__ qf, const ushort_t* __restrict__ kf,
    const ushort_t* __restrict__ vf, const float* __restrict__ lobo,
    const float* __restrict__ qknf, float* __restrict__ y) {
  const int f = blockIdx.x;            // 1024 blocks
  const int bh = f & 31;
  const int slot = f >> 5;             // 0..31
  int tq;
  if (slot < 8)       tq = 31 - slot;  // 31..24
  else if (slot < 16) tq = 8 + slot;   // 16..23
  else if (slot < 24) tq = 31 - slot;  // 15..8
  else                tq = slot - 24;  // 0..7
  const int b = bh >> 4;
  const int h = bh & 15;
  const int g = h >> 2;

  __shared__ ushort_t KV[12288];       // [K: 8 x 512 | V: 16 x 512] per kt
  __shared__ ushort_t Ps[4 * 1088];    // per-wave 16 rows x 68

  const int tid = threadIdx.x;
  const int wave = tid >> 6, lane = tid & 63;
  const int quad = lane >> 4, l16 = lane & 15;
  ushort_t* PsW = &Ps[wave * 1088];

  short8 bones;
  {
    short bv = (l16 == 0) ? (short)0x3F80 : (short)0;
#pragma unroll
    for (int j = 0; j < 8; j++) bones[j] = bv;
  }

  const ushort_t* qbase = qf + (size_t)(b * 16 + h) * 131072 + lane * 8;
  short8 aq0 = *(const short8*)&qbase[(size_t)(tq * 8 + wave * 2 + 0) * 512];
  short8 aq1 = *(const short8*)&qbase[(size_t)(tq * 8 + wave * 2 + 1) * 512];

  f32x4 o[9];
#pragma unroll
  for (int nv = 0; nv < 9; nv++) o[nv] = (f32x4){0.f, 0.f, 0.f, 0.f};

  const float gsc = qknf[0];
  const float sinkp = __expf(lobo[h] - gsc);

  const int row = tq * 64 + wave * 16 + quad * 4;   // +r

  // per-lane global pointers for staging (lane*8 element offset built in)
  const ushort_t* kgl = kf + (size_t)(b * 4 + g) * 131072 + lane * 8;
  const ushort_t* vgl = vf + (size_t)(b * 4 + g) * 262144 + lane * 8;

  for (int kt = 0; kt <= tq; kt++) {
    // ---- stage K+V tile into LDS (barriers wrap staging ONLY) ----
    __syncthreads();   // previous iteration's KV reads complete
    {
      const ushort_t* gk = kgl + (size_t)kt * 4096;
      const ushort_t* gv = vgl + (size_t)kt * 8192;
      GLD_LDS16(gk + (wave * 2 + 0) * 512, &KV[(wave * 2 + 0) * 512]);
      GLD_LDS16(gk + (wave * 2 + 1) * 512, &KV[(wave * 2 + 1) * 512]);
#pragma unroll
      for (int j = 0; j < 4; j++)
        GLD_LDS16(gv + (wave * 4 + j) * 512, &KV[4096 + (wave * 4 + j) * 512]);
    }
    __syncthreads();   // staging complete (implicit vmcnt drain)

    // ---- QK: K frags from LDS in two batches of 4 ----
    f32x4 s[4];
#pragma unroll
    for (int nt = 0; nt < 4; nt++) s[nt] = (f32x4){0.f, 0.f, 0.f, 0.f};
    {
      short8 kb[4];
#pragma unroll
      for (int u = 0; u < 4; u++)
        kb[u] = *(const short8*)&KV[u * 512 + lane * 8];
      __builtin_amdgcn_s_setprio(1);
#pragma unroll
      for (int nt = 0; nt < 4; nt++)
        s[nt] = __builtin_amdgcn_mfma_f32_16x16x32_bf16(aq0, kb[nt], s[nt], 0, 0, 0);
      __builtin_amdgcn_s_setprio(0);
#pragma unroll
      for (int u = 0; u < 4; u++)
        kb[u] = *(const short8*)&KV[(4 + u) * 512 + lane * 8];
      __builtin_amdgcn_s_setprio(1);
#pragma unroll
      for (int nt = 0; nt < 4; nt++)
        s[nt] = __builtin_amdgcn_mfma_f32_16x16x32_bf16(aq1, kb[nt], s[nt], 0, 0, 0);
      __builtin_amdgcn_s_setprio(0);
    }

    // ---- mask + exp + bf16 store; causal cmp only on diagonal iter ----
    if (kt == tq) {
#pragma unroll
      for (int nt = 0; nt < 4; nt++) {
        int key = kt * 64 + l16 + nt * 16;
#pragma unroll
        for (int r = 0; r < 4; r++) {
          float pv = (key <= row + r) ? __expf(fmaf(s[nt][r], gsc, -gsc)) : 0.f;
          PsW[(quad * 4 + r) * 68 + nt * 16 + l16] = f2bf_hw(pv);
        }
      }
    } else {
#pragma unroll
      for (int nt = 0; nt < 4; nt++)
#pragma unroll
        for (int r = 0; r < 4; r++)
          PsW[(quad * 4 + r) * 68 + nt * 16 + l16] =
              f2bf_hw(__expf(fmaf(s[nt][r], gsc, -gsc)));
    }

    // ---- read P fragments, PV with V frags from LDS (4 batches of 4) ----
    short8 ap0 = *(const short8*)&PsW[l16 * 68 + quad * 8];
    short8 ap1 = *(const short8*)&PsW[l16 * 68 + 32 + quad * 8];
    {
      short8 vb[4];
#pragma unroll
      for (int u = 0; u < 4; u++)
        vb[u] = *(const short8*)&KV[4096 + u * 512 + lane * 8];
      __builtin_amdgcn_s_setprio(1);
#pragma unroll
      for (int nv = 0; nv < 4; nv++)
        o[nv] = __builtin_amdgcn_mfma_f32_16x16x32_bf16(ap0, vb[nv], o[nv], 0, 0, 0);
      __builtin_amdgcn_s_setprio(0);
#pragma unroll
      for (int u = 0; u < 4; u++)
        vb[u] = *(const short8*)&KV[4096 + (4 + u) * 512 + lane * 8];
      __builtin_amdgcn_s_setprio(1);
#pragma unroll
      for (int nv = 0; nv < 4; nv++)
        o[4 + nv] = __builtin_amdgcn_mfma_f32_16x16x32_bf16(ap0, vb[nv], o[4 + nv], 0, 0, 0);
      o[8] = __builtin_amdgcn_mfma_f32_16x16x32_bf16(ap0, bones, o[8], 0, 0, 0);
      o[8] = __builtin_amdgcn_mfma_f32_16x16x32_bf16(ap1, bones, o[8], 0, 0, 0);
      __builtin_amdgcn_s_setprio(0);
#pragma unroll
      for (int u = 0; u < 4; u++)
        vb[u] = *(const short8*)&KV[4096 + (8 + u) * 512 + lane * 8];
      __builtin_amdgcn_s_setprio(1);
#pragma unroll
      for (int nv = 0; nv < 4; nv++)
        o[nv] = __builtin_amdgcn_mfma_f32_16x16x32_bf16(ap1, vb[nv], o[nv], 0, 0, 0);
      __builtin_amdgcn_s_setprio(0);
#pragma unroll
      for (int u = 0; u < 4; u++)
        vb[u] = *(const short8*)&KV[4096 + (12 + u) * 512 + lane * 8];
      __builtin_amdgcn_s_setprio(1);
#pragma unroll
      for (int nv = 0; nv < 4; nv++)
        o[4 + nv] = __builtin_amdgcn_mfma_f32_16x16x32_bf16(ap1, vb[nv], o[4 + nv], 0, 0, 0);
      __builtin_amdgcn_s_setprio(0);
    }
  }

  // epilogue: l = sink + mfma row-sum (col 0 of o[8]); normalize; head-sum
#pragma unroll
  for (int r = 0; r < 4; r++) {
    float lm = __shfl(o[8][r], lane & 48, 64);
    float invl = 1.0f / (lm + sinkp);
    size_t gRow = (size_t)b * T_ + row + r;
#pragma unroll
    for (int nv = 0; nv < 8; nv++)
      atomicAdd(&y[gRow * 128 + nv * 16 + l16], o[nv][r] * invl);
  }
}

// ---------------------------------------------------------------------------
// Kernel 4: out = y[4096][128] @ Wproj[128][1024] via bf16 MFMA.
// ---------------------------------------------------------------------------
__global__ __launch_bounds__(256) void out_proj(
    const float* __restrict__ y, const ushort_t* __restrict__ wpf,
    float* __restrict__ out) {
  __shared__ ushort_t yl[128 * 136];
  const int tid = threadIdx.x;
  const int wave = tid >> 6, lane = tid & 63;
  const int quad = lane >> 4, l16 = lane & 15;
  const int n0 = blockIdx.x * 128, m0 = blockIdx.y * 128;
  const int wm = (wave & 1) * 64, wn = (wave >> 1) * 64;

#pragma unroll
  for (int it = 0; it < 8; it++) {
    int p = it * 256 + tid;
    int row = p >> 4, c8 = p & 15;
    const float* src = &y[(size_t)(m0 + row) * 128 + c8 * 8];
    float4 v0 = *(const float4*)&src[0];
    float4 v1 = *(const float4*)&src[4];
    float fv[8] = {v0.x, v0.y, v0.z, v0.w, v1.x, v1.y, v1.z, v1.w};
    short8 hv;
#pragma unroll
    for (int c = 0; c < 8; c++) hv[c] = (short)f2bf(fv[c]);
    *(short8*)&yl[row * 136 + c8 * 8] = hv;
  }
  __syncthreads();

  f32x4 acc[4][4];
#pragma unroll
  for (int i = 0; i < 4; i++)
#pragma unroll
    for (int j = 0; j < 4; j++) acc[i][j] = (f32x4){0.f, 0.f, 0.f, 0.f};

#pragma unroll
  for (int ks = 0; ks < 4; ks++) {
    short8 af[4], bfr[4];
#pragma unroll
    for (int i = 0; i < 4; i++)
      af[i] = *(const short8*)&yl[(wm + 16 * i + l16) * 136 + (ks * 4 + quad) * 8];
    const ushort_t* wb = wpf + (((size_t)(n0 >> 7) * 4 + ks) * 8) * 512;
#pragma unroll
    for (int j = 0; j < 4; j++)
      bfr[j] = *(const short8*)&wb[((size_t)((wn >> 4) + j)) * 512 + lane * 8];
#pragma unroll
    for (int i = 0; i < 4; i++)
#pragma unroll
      for (int j = 0; j < 4; j++)
        acc[i][j] = __builtin_amdgcn_mfma_f32_16x16x32_bf16(
            af[i], bfr[j], acc[i][j], 0, 0, 0);
  }

#pragma unroll
  for (int i = 0; i < 4; i++) {
    int m = m0 + wm + 16 * i + quad * 4;
#pragma unroll
    for (int j = 0; j < 4; j++) {
      int n = n0 + wn + 16 * j + l16;
#pragma unroll
      for (int r = 0; r < 4; r++)
        out[(size_t)(m + r) * 1024 + n] = acc[i][j][r];
    }
  }
}

// ---------------------------------------------------------------------------
extern "C" void kernel_launch(void* const* d_in, const int* in_sizes, int n_in,
                              void* d_out, int out_size, void* d_ws, size_t ws_size,
                              hipStream_t stream) {
  const float* x     = (const float*)d_in[0];
  const float* Wq    = (const float*)d_in[2];
  const float* Wk    = (const float*)d_in[3];
  const float* Wv    = (const float*)d_in[4];
  const float* Wproj = (const float*)d_in[5];
  const float* lobo  = (const float*)d_in[6];
  const float* qknf  = (const float*)d_in[7];
  float* out = (float*)d_out;

  // ws: [qkv f32 29.4MB | xb 16.8MB | wt 7.3MB | wpf 0.25MB]; qf/kf/vf/y alias xb.
  float* qkv = (float*)d_ws;                                    // 7,340,032 f32
  ushort_t* xb = (ushort_t*)(qkv + (size_t)B_ * T_ * NQKV);     // 8,388,608 bf16
  ushort_t* wt = xb + (size_t)B_ * T_ * KS2;                    // 3,670,016 bf16
  ushort_t* wpf = wt + (size_t)NQKV * KS2;                      //   131,072 bf16
  ushort_t* qf = xb;                                            // 4,194,304 bf16
  ushort_t* kf = qf + (size_t)B_ * H_ * T_ * 64;                // 1,048,576 bf16
  ushort_t* vf = kf + (size_t)B_ * G_ * T_ * 64;                // 2,097,152 bf16
  float* y = (float*)(vf + (size_t)B_ * G_ * T_ * 128);         //   524,288 f32

  // 5 dispatches (was 9): prep -> gemm -> rope_scatter -> attn -> out_proj
  prep<<<2560, 256, 0, stream>>>(x, Wq, Wk, Wv, Wproj, xb, wt, wpf);

  dim3 gg(NQKV / 128, (B_ * T_) / 128);
  gemm_qkv_mfma<<<gg, 256, 0, stream>>>(xb, wt, qkv);

  rope_scatter<<<29184, 256, 0, stream>>>(qkv, qf, kf, vf, y);

  attn<<<B_ * H_ * 32, 256, 0, stream>>>(qf, kf, vf, lobo, qknf, y);

  dim3 go(8, 32);
  out_proj<<<go, 256, 0, stream>>>(y, wpf, out);
}

// Round 14
// 214.463 us; speedup vs baseline: 1.1357x; 1.0084x over previous
//
#include <hip/hip_runtime.h>
#include <hip/hip_bf16.h>
#include <math.h>

#define B_ 2
#define T_ 2048
#define C_ 1024
#define H_ 16
#define G_ 4
#define DQK_ 64
#define DV_ 128
#define NQKV 1792   // H*DQK + G*DQK + G*DV
#define QKW 1280    // qkv row stride AFTER vscatter fusion: [Q 1024 | K 256]
#define KS2 2048    // compact split storage: [hi | lo]
// Variable-K split GEMM: Q/K columns (n<1280) use 2048 K-depth
// (hi·hi + lo·hi); V columns (n>=1280) use 1024 (hi·hi only).
// Operand rows chunk-XOR-swizzled: chunk c of row r at phys chunk c^((r>>1)&3).

typedef __attribute__((ext_vector_type(8))) short short8;
typedef __attribute__((ext_vector_type(4))) float f32x4;
typedef unsigned short ushort_t;

__device__ inline ushort_t f2bf(float f) {
  union { float f; unsigned int u; } v; v.f = f;
  unsigned int r = (v.u + 0x7FFFu + ((v.u >> 16) & 1u)) >> 16;  // RNE
  return (ushort_t)r;
}
__device__ inline float bf2f(ushort_t h) {
  union { unsigned int u; float f; } v; v.u = ((unsigned int)h) << 16;
  return v.f;
}
// single-instruction RNE f32->bf16 (dst.lo = cvt(src)); P is finite in (0,1]
__device__ inline ushort_t f2bf_hw(float f) {
  unsigned int u;
  asm("v_cvt_pk_bf16_f32 %0, %1, %1" : "=v"(u) : "v"(f));
  return (ushort_t)u;
}

#define GLD_LDS16(g, l)                                              \
  __builtin_amdgcn_global_load_lds(                                  \
      (const __attribute__((address_space(1))) void*)(g),            \
      (__attribute__((address_space(3))) void*)(l), 16, 0, 0)

// ---------------------------------------------------------------------------
// Kernel 0 (FUSED): prep = cast_x | cast_w | cast_wp by blockIdx range.
// ---------------------------------------------------------------------------
__global__ __launch_bounds__(256) void prep(
    const float* __restrict__ x, const float* __restrict__ Wq,
    const float* __restrict__ Wk, const float* __restrict__ Wv,
    const float* __restrict__ Wproj, ushort_t* __restrict__ xb,
    ushort_t* __restrict__ wt, ushort_t* __restrict__ wpf) {
  __shared__ float tile[64][65];
  const int bid = blockIdx.x;
  const int tid = threadIdx.x;

  if (bid < 2048) {
    // ---- cast_x ----
    int idx = bid * 256 + tid;   // 524288
    int m = idx >> 7;
    int c8 = idx & 127;
    const float* src = &x[(size_t)m * 1024 + c8 * 8];
    float4 v0 = *(const float4*)&src[0];
    float4 v1 = *(const float4*)&src[4];
    float f[8] = {v0.x, v0.y, v0.z, v0.w, v1.x, v1.y, v1.z, v1.w};
    short8 hv, lv;
#pragma unroll
    for (int c = 0; c < 8; c++) {
      ushort_t h = f2bf(f[c]);
      hv[c] = (short)h;
      lv[c] = (short)f2bf(f[c] - bf2f(h));
    }
    int key = (m >> 1) & 3;
    int phys = (c8 & ~3) * 8 + ((c8 & 3) ^ key) * 8;
    ushort_t* row = xb + (size_t)m * KS2;
    *(short8*)&row[phys] = hv;
    *(short8*)&row[1024 + phys] = lv;
  } else if (bid < 2496) {
    // ---- cast_w ----
    const int wid = bid - 2048;          // 0..447 = 28 x 16
    const int n0 = (wid % 28) * 64;
    const int k0 = (wid / 28) * 64;

    const float* Wp; int ldw, noff;
    if (n0 < 1024)      { Wp = Wq; ldw = 1024; noff = n0; }
    else if (n0 < 1280) { Wp = Wk; ldw = 256;  noff = n0 - 1024; }
    else                { Wp = Wv; ldw = 512;  noff = n0 - 1280; }

#pragma unroll
    for (int it = 0; it < 4; it++) {
      int fi = it * 256 + tid;
      int kk = fi >> 4;
      int nc = (fi & 15) * 4;
      float4 v = *(const float4*)&Wp[(size_t)(k0 + kk) * ldw + noff + nc];
      tile[nc + 0][kk] = v.x; tile[nc + 1][kk] = v.y;
      tile[nc + 2][kk] = v.z; tile[nc + 3][kk] = v.w;
    }
    __syncthreads();
    int nn = tid >> 2, seg = tid & 3;
    int n = n0 + nn;
    int key = (n >> 1) & 3;
    ushort_t* row = wt + (size_t)n * KS2;
#pragma unroll
    for (int j = 0; j < 2; j++) {
      short8 hv;
#pragma unroll
      for (int u = 0; u < 8; u++)
        hv[u] = (short)f2bf(tile[nn][seg * 16 + j * 8 + u]);
      int c8 = (k0 >> 3) + seg * 2 + j;
      int phys = (c8 & ~3) * 8 + ((c8 & 3) ^ key) * 8;
      *(short8*)&row[phys] = hv;
    }
  } else {
    // ---- cast_wp ----
    int idx = (bid - 2496) * 256 + tid;  // 16384
    int n = idx & 1023;
    int kc = idx >> 10;                  // 0..15 (chunk of 8 k's)
    short8 v;
#pragma unroll
    for (int j = 0; j < 8; j++)
      v[j] = (short)f2bf(Wproj[(size_t)(kc * 8 + j) * 1024 + n]);
    size_t off = (((size_t)(n >> 7) * 4 + (kc >> 2)) * 8 + ((n >> 4) & 7)) * 512 +
                 ((kc & 3) * 16 + (n & 15)) * 8;
    *(short8*)&wpf[off] = v;
  }
}

// ---------------------------------------------------------------------------
// Kernel 1: bf16-MFMA QKV GEMM, BK=64.  V-columns (n0>=1280) write DIRECTLY
// to vf in bf16 PV-fragment layout (fused vscatter).
// ROUND 14 RACE FIX: round 13 placed vf inside the xb region (aliased!) so
// gemm's vf writes corrupted xb rows still being read by other blocks.
// Now qkv's row stride shrinks to QKW=1280 (V cols never written) and vf
// lives in the FREED tail of the qkv region — gemm reads {xb,wt}, writes
// {qkv,vf}, zero overlap.
// ---------------------------------------------------------------------------
__global__ __launch_bounds__(256) void gemm_qkv_mfma(
    const ushort_t* __restrict__ xb, const ushort_t* __restrict__ wt,
    float* __restrict__ qkv, ushort_t* __restrict__ vf) {
  __shared__ ushort_t At[128 * 64];
  __shared__ ushort_t Bt[128 * 64];
  const int tid = threadIdx.x;
  const int wave = tid >> 6, lane = tid & 63;
  const int quad = lane >> 4, l16 = lane & 15;
  const int m0 = blockIdx.y * 128, n0 = blockIdx.x * 128;
  const int wm = (wave & 1) * 64, wn = (wave >> 1) * 64;
  const int key = (l16 >> 1) & 3;
  const int ntiles = (n0 >= 1280) ? 16 : 32;

  f32x4 acc[4][4];
#pragma unroll
  for (int i = 0; i < 4; i++)
#pragma unroll
    for (int j = 0; j < 4; j++) acc[i][j] = (f32x4){0.f, 0.f, 0.f, 0.f};

  const int rA = wave * 32 + (lane >> 3);
  const int cA = (lane & 7) * 8;
  const ushort_t* gA = xb + (size_t)(m0 + rA) * KS2 + cA;
  const ushort_t* gB = wt + (size_t)(n0 + rA) * KS2 + cA;

  for (int kt = 0; kt < ntiles; kt++) {
    const int ca = kt * 64;                         // A walks hi then lo
    const int cb = (kt < 16 ? kt : kt - 16) * 64;   // B wraps within hi
    __syncthreads();
#pragma unroll
    for (int j = 0; j < 4; j++) {
      GLD_LDS16(gA + ca + (size_t)(8 * j) * KS2, &At[(wave * 32 + 8 * j) * 64]);
      GLD_LDS16(gB + cb + (size_t)(8 * j) * KS2, &Bt[(wave * 32 + 8 * j) * 64]);
    }
    __syncthreads();

#pragma unroll
    for (int s = 0; s < 2; s++) {
      const int off = s * 32 + ((quad ^ key) * 8);
      short8 af[4], bf[4];
#pragma unroll
      for (int i = 0; i < 4; i++)
        af[i] = *(const short8*)&At[(wm + 16 * i + l16) * 64 + off];
#pragma unroll
      for (int j = 0; j < 4; j++)
        bf[j] = *(const short8*)&Bt[(wn + 16 * j + l16) * 64 + off];
#pragma unroll
      for (int i = 0; i < 4; i++)
#pragma unroll
        for (int j = 0; j < 4; j++)
          acc[i][j] = __builtin_amdgcn_mfma_f32_16x16x32_bf16(
              af[i], bf[j], acc[i][j], 0, 0, 0);
    }
  }

  if (n0 >= 1280) {
    // ---- fused vscatter: bf16 cast + PV B-fragment layout store ----
    // dv = wn+16*jn+l16 (n0-1280 is 128-aligned); nv=(wn>>4)+jn; l16v=l16;
    // per element m: b=m>>11, t=m&2047 -> (tk,ks,qd,jj).  Matches vscatter.
    const int g = (n0 - 1280) >> 7;
    ushort_t* vg = vf + (size_t)g * 262144;   // + b*4*262144 added per elem
#pragma unroll
    for (int i = 0; i < 4; i++) {
      int mbase = m0 + wm + 16 * i + quad * 4;
#pragma unroll
      for (int jn = 0; jn < 4; jn++) {
        int nv = (wn >> 4) + jn;
#pragma unroll
        for (int r = 0; r < 4; r++) {
          int m = mbase + r;
          int b = m >> 11, t = m & 2047;
          int tk = t >> 6, ks = (t >> 5) & 1, qd = (t >> 3) & 3, jj = t & 7;
          size_t off = (size_t)b * 4 * 262144 +
                       ((size_t)(tk * 16 + ks * 8 + nv) * 4 + qd) * 128 +
                       l16 * 8 + jj;
          vg[off] = f2bf(acc[i][jn][r]);
        }
      }
    }
  } else {
#pragma unroll
    for (int i = 0; i < 4; i++) {
      int m = m0 + wm + 16 * i + quad * 4;
#pragma unroll
      for (int j = 0; j < 4; j++) {
        int n = n0 + wn + 16 * j + l16;
#pragma unroll
        for (int r = 0; r < 4; r++)
          qkv[(size_t)(m + r) * QKW + n] = acc[i][j][r];
      }
    }
  }
}

// ---------------------------------------------------------------------------
// Kernel 2 (FUSED): rope_scatter = rope_norm | y-zero by blockIdx range.
// qkv row stride is QKW=1280 (Q|K only).
// ---------------------------------------------------------------------------
__global__ __launch_bounds__(256) void rope_scatter(
    const float* __restrict__ qkv, ushort_t* __restrict__ qf,
    ushort_t* __restrict__ kf, float* __restrict__ y) {
  const int bid = blockIdx.x;
  const int tid = threadIdx.x;

  if (bid < 20480) {
    // ---- rope_norm ----
    const int NQ = B_ * T_ * H_;
    int vec = bid * 4 + (tid >> 6);
    int d = tid & 63;

    size_t src; int t, b, isq; ushort_t* dstbase;
    if (vec < NQ) {
      int h = vec % H_; int bt = vec / H_;
      t = bt % T_; b = bt / T_;
      src = (size_t)bt * QKW + h * 64 + d;
      dstbase = qf + (size_t)(b * 16 + h) * 131072;
      isq = 1;
    } else {
      int vk = vec - NQ;
      int g = vk % G_; int bt = vk / G_;
      t = bt % T_; b = bt / T_;
      src = (size_t)bt * QKW + 1024 + g * 64 + d;
      dstbase = kf + (size_t)(b * 4 + g) * 131072;
      isq = 0;
    }
    float val = qkv[src];
    int i = d & 31;
    float inv = exp2f(-(float)i * 0.4152410118074239f);  // log2(10000)/32
    float ang = (float)t * inv;
    float sn, cs;
    __sincosf(ang, &sn, &cs);
    float partner = __shfl(val, d ^ 32, 64);
    float r = (d < 32) ? (val * cs - partner * sn) : (val * cs + partner * sn);
    float ss = r * r;
#pragma unroll
    for (int off = 32; off; off >>= 1) ss += __shfl_xor(ss, off, 64);
    r *= 1.0f / (sqrtf(ss) + 1e-6f);

    int kt = t >> 6, tt = t & 63;
    int l16v = tt & 15;
    int ks = d >> 5, quad = (d >> 3) & 3, j = d & 7;
    size_t off2;
    if (isq) {
      int wavei = tt >> 4;
      off2 = ((size_t)(kt * 8 + wavei * 2 + ks) * 4 + quad) * 128 + l16v * 8 + j;
    } else {
      int nt = tt >> 4;
      off2 = ((size_t)(kt * 8 + ks * 4 + nt) * 4 + quad) * 128 + l16v * 8 + j;
    }
    dstbase[off2] = f2bf(r);
  } else {
    // ---- zero y ----
    int idx = (bid - 20480) * 256 + tid;   // 131072 float4s
    *(float4*)&y[(size_t)idx * 4] = (float4){0.f, 0.f, 0.f, 0.f};
  }
}

// ---------------------------------------------------------------------------
// Kernel 3: bf16-MFMA causal flash attention (ROUND-10 BODY — best passing:
// 65.6us).  Single-buffer K/V LDS staging (2 barriers wrap staging only),
// 4 blocks/CU declared, serpentine balanced slot map, v_cvt_pk f2bf + fma
// exp arg.
// ---------------------------------------------------------------------------
__global__ __launch_bounds__(256, 4) void attn(
    const ushort_t* __restrict__ qf, const ushort_t* __restrict__ kf,
    const ushort_t* __restrict__ vf, const float* __restrict__ lobo,
    const float* __restrict__ qknf, float* __restrict__ y) {
  const int f = blockIdx.x;            // 1024 blocks
  const int bh = f & 31;
  const int slot = f >> 5;             // 0..31
  int tq;
  if (slot < 8)       tq = 31 - slot;  // 31..24
  else if (slot < 16) tq = 8 + slot;   // 16..23
  else if (slot < 24) tq = 31 - slot;  // 15..8
  else                tq = slot - 24;  // 0..7
  const int b = bh >> 4;
  const int h = bh & 15;
  const int g = h >> 2;

  __shared__ ushort_t KV[12288];       // [K: 8 x 512 | V: 16 x 512] per kt
  __shared__ ushort_t Ps[4 * 1088];    // per-wave 16 rows x 68

  const int tid = threadIdx.x;
  const int wave = tid >> 6, lane = tid & 63;
  const int quad = lane >> 4, l16 = lane & 15;
  ushort_t* PsW = &Ps[wave * 1088];

  short8 bones;
  {
    short bv = (l16 == 0) ? (short)0x3F80 : (short)0;
#pragma unroll
    for (int j = 0; j < 8; j++) bones[j] = bv;
  }

  const ushort_t* qbase = qf + (size_t)(b * 16 + h) * 131072 + lane * 8;
  short8 aq0 = *(const short8*)&qbase[(size_t)(tq * 8 + wave * 2 + 0) * 512];
  short8 aq1 = *(const short8*)&qbase[(size_t)(tq * 8 + wave * 2 + 1) * 512];

  f32x4 o[9];
#pragma unroll
  for (int nv = 0; nv < 9; nv++) o[nv] = (f32x4){0.f, 0.f, 0.f, 0.f};

  const float gsc = qknf[0];
  const float sinkp = __expf(lobo[h] - gsc);

  const int row = tq * 64 + wave * 16 + quad * 4;   // +r

  // per-lane global pointers for staging (lane*8 element offset built in)
  const ushort_t* kgl = kf + (size_t)(b * 4 + g) * 131072 + lane * 8;
  const ushort_t* vgl = vf + (size_t)(b * 4 + g) * 262144 + lane * 8;

  for (int kt = 0; kt <= tq; kt++) {
    // ---- stage K+V tile into LDS (barriers wrap staging ONLY) ----
    __syncthreads();   // previous iteration's KV reads complete
    {
      const ushort_t* gk = kgl + (size_t)kt * 4096;
      const ushort_t* gv = vgl + (size_t)kt * 8192;
      GLD_LDS16(gk + (wave * 2 + 0) * 512, &KV[(wave * 2 + 0) * 512]);
      GLD_LDS16(gk + (wave * 2 + 1) * 512, &KV[(wave * 2 + 1) * 512]);
#pragma unroll
      for (int j = 0; j < 4; j++)
        GLD_LDS16(gv + (wave * 4 + j) * 512, &KV[4096 + (wave * 4 + j) * 512]);
    }
    __syncthreads();   // staging complete (implicit vmcnt drain)

    // ---- QK: K frags from LDS in two batches of 4 ----
    f32x4 s[4];
#pragma unroll
    for (int nt = 0; nt < 4; nt++) s[nt] = (f32x4){0.f, 0.f, 0.f, 0.f};
    {
      short8 kb[4];
#pragma unroll
      for (int u = 0; u < 4; u++)
        kb[u] = *(const short8*)&KV[u * 512 + lane * 8];
      __builtin_amdgcn_s_setprio(1);
#pragma unroll
      for (int nt = 0; nt < 4; nt++)
        s[nt] = __builtin_amdgcn_mfma_f32_16x16x32_bf16(aq0, kb[nt], s[nt], 0, 0, 0);
      __builtin_amdgcn_s_setprio(0);
#pragma unroll
      for (int u = 0; u < 4; u++)
        kb[u] = *(const short8*)&KV[(4 + u) * 512 + lane * 8];
      __builtin_amdgcn_s_setprio(1);
#pragma unroll
      for (int nt = 0; nt < 4; nt++)
        s[nt] = __builtin_amdgcn_mfma_f32_16x16x32_bf16(aq1, kb[nt], s[nt], 0, 0, 0);
      __builtin_amdgcn_s_setprio(0);
    }

    // ---- mask + exp + bf16 store; causal cmp only on diagonal iter ----
    if (kt == tq) {
#pragma unroll
      for (int nt = 0; nt < 4; nt++) {
        int key = kt * 64 + l16 + nt * 16;
#pragma unroll
        for (int r = 0; r < 4; r++) {
          float pv = (key <= row + r) ? __expf(fmaf(s[nt][r], gsc, -gsc)) : 0.f;
          PsW[(quad * 4 + r) * 68 + nt * 16 + l16] = f2bf_hw(pv);
        }
      }
    } else {
#pragma unroll
      for (int nt = 0; nt < 4; nt++)
#pragma unroll
        for (int r = 0; r < 4; r++)
          PsW[(quad * 4 + r) * 68 + nt * 16 + l16] =
              f2bf_hw(__expf(fmaf(s[nt][r], gsc, -gsc)));
    }

    // ---- read P fragments, PV with V frags from LDS (4 batches of 4) ----
    short8 ap0 = *(const short8*)&PsW[l16 * 68 + quad * 8];
    short8 ap1 = *(const short8*)&PsW[l16 * 68 + 32 + quad * 8];
    {
      short8 vb[4];
#pragma unroll
      for (int u = 0; u < 4; u++)
        vb[u] = *(const short8*)&KV[4096 + u * 512 + lane * 8];
      __builtin_amdgcn_s_setprio(1);
#pragma unroll
      for (int nv = 0; nv < 4; nv++)
        o[nv] = __builtin_amdgcn_mfma_f32_16x16x32_bf16(ap0, vb[nv], o[nv], 0, 0, 0);
      __builtin_amdgcn_s_setprio(0);
#pragma unroll
      for (int u = 0; u < 4; u++)
        vb[u] = *(const short8*)&KV[4096 + (4 + u) * 512 + lane * 8];
      __builtin_amdgcn_s_setprio(1);
#pragma unroll
      for (int nv = 0; nv < 4; nv++)
        o[4 + nv] = __builtin_amdgcn_mfma_f32_16x16x32_bf16(ap0, vb[nv], o[4 + nv], 0, 0, 0);
      o[8] = __builtin_amdgcn_mfma_f32_16x16x32_bf16(ap0, bones, o[8], 0, 0, 0);
      o[8] = __builtin_amdgcn_mfma_f32_16x16x32_bf16(ap1, bones, o[8], 0, 0, 0);
      __builtin_amdgcn_s_setprio(0);
#pragma unroll
      for (int u = 0; u < 4; u++)
        vb[u] = *(const short8*)&KV[4096 + (8 + u) * 512 + lane * 8];
      __builtin_amdgcn_s_setprio(1);
#pragma unroll
      for (int nv = 0; nv < 4; nv++)
        o[nv] = __builtin_amdgcn_mfma_f32_16x16x32_bf16(ap1, vb[nv], o[nv], 0, 0, 0);
      __builtin_amdgcn_s_setprio(0);
#pragma unroll
      for (int u = 0; u < 4; u++)
        vb[u] = *(const short8*)&KV[4096 + (12 + u) * 512 + lane * 8];
      __builtin_amdgcn_s_setprio(1);
#pragma unroll
      for (int nv = 0; nv < 4; nv++)
        o[4 + nv] = __builtin_amdgcn_mfma_f32_16x16x32_bf16(ap1, vb[nv], o[4 + nv], 0, 0, 0);
      __builtin_amdgcn_s_setprio(0);
    }
  }

  // epilogue: l = sink + mfma row-sum (col 0 of o[8]); normalize; head-sum
#pragma unroll
  for (int r = 0; r < 4; r++) {
    float lm = __shfl(o[8][r], lane & 48, 64);
    float invl = 1.0f / (lm + sinkp);
    size_t gRow = (size_t)b * T_ + row + r;
#pragma unroll
    for (int nv = 0; nv < 8; nv++)
      atomicAdd(&y[gRow * 128 + nv * 16 + l16], o[nv][r] * invl);
  }
}

// ---------------------------------------------------------------------------
// Kernel 4: out = y[4096][128] @ Wproj[128][1024] via bf16 MFMA.
// ---------------------------------------------------------------------------
__global__ __launch_bounds__(256) void out_proj(
    const float* __restrict__ y, const ushort_t* __restrict__ wpf,
    float* __restrict__ out) {
  __shared__ ushort_t yl[128 * 136];
  const int tid = threadIdx.x;
  const int wave = tid >> 6, lane = tid & 63;
  const int quad = lane >> 4, l16 = lane & 15;
  const int n0 = blockIdx.x * 128, m0 = blockIdx.y * 128;
  const int wm = (wave & 1) * 64, wn = (wave >> 1) * 64;

#pragma unroll
  for (int it = 0; it < 8; it++) {
    int p = it * 256 + tid;
    int row = p >> 4, c8 = p & 15;
    const float* src = &y[(size_t)(m0 + row) * 128 + c8 * 8];
    float4 v0 = *(const float4*)&src[0];
    float4 v1 = *(const float4*)&src[4];
    float fv[8] = {v0.x, v0.y, v0.z, v0.w, v1.x, v1.y, v1.z, v1.w};
    short8 hv;
#pragma unroll
    for (int c = 0; c < 8; c++) hv[c] = (short)f2bf(fv[c]);
    *(short8*)&yl[row * 136 + c8 * 8] = hv;
  }
  __syncthreads();

  f32x4 acc[4][4];
#pragma unroll
  for (int i = 0; i < 4; i++)
#pragma unroll
    for (int j = 0; j < 4; j++) acc[i][j] = (f32x4){0.f, 0.f, 0.f, 0.f};

#pragma unroll
  for (int ks = 0; ks < 4; ks++) {
    short8 af[4], bfr[4];
#pragma unroll
    for (int i = 0; i < 4; i++)
      af[i] = *(const short8*)&yl[(wm + 16 * i + l16) * 136 + (ks * 4 + quad) * 8];
    const ushort_t* wb = wpf + (((size_t)(n0 >> 7) * 4 + ks) * 8) * 512;
#pragma unroll
    for (int j = 0; j < 4; j++)
      bfr[j] = *(const short8*)&wb[((size_t)((wn >> 4) + j)) * 512 + lane * 8];
#pragma unroll
    for (int i = 0; i < 4; i++)
#pragma unroll
      for (int j = 0; j < 4; j++)
        acc[i][j] = __builtin_amdgcn_mfma_f32_16x16x32_bf16(
            af[i], bfr[j], acc[i][j], 0, 0, 0);
  }

#pragma unroll
  for (int i = 0; i < 4; i++) {
    int m = m0 + wm + 16 * i + quad * 4;
#pragma unroll
    for (int j = 0; j < 4; j++) {
      int n = n0 + wn + 16 * j + l16;
#pragma unroll
      for (int r = 0; r < 4; r++)
        out[(size_t)(m + r) * 1024 + n] = acc[i][j][r];
    }
  }
}

// ---------------------------------------------------------------------------
extern "C" void kernel_launch(void* const* d_in, const int* in_sizes, int n_in,
                              void* d_out, int out_size, void* d_ws, size_t ws_size,
                              hipStream_t stream) {
  const float* x     = (const float*)d_in[0];
  const float* Wq    = (const float*)d_in[2];
  const float* Wk    = (const float*)d_in[3];
  const float* Wv    = (const float*)d_in[4];
  const float* Wproj = (const float*)d_in[5];
  const float* lobo  = (const float*)d_in[6];
  const float* qknf  = (const float*)d_in[7];
  float* out = (float*)d_out;

  // ws layout (53.7MB total, unchanged footprint):
  //  [0, 20.97MB)   qkv f32, row stride QKW=1280 (Q|K only)
  //  [20.97, 25.17) vf bf16 (2,097,152) — freed V-tail of old qkv region;
  //                 written by gemm, read by attn.  NO alias with xb!
  //  [29.36, 46.14) xb bf16 (8,388,608); qf/kf/y alias xb AFTER gemm is done
  //  [46.14, 53.48) wt bf16;  [53.48, 53.74) wpf bf16
  float* qkvfull = (float*)d_ws;                                  // historical region
  float* qkv = qkvfull;                                           // 4096 x QKW f32
  ushort_t* vf = (ushort_t*)(qkvfull + (size_t)B_ * T_ * QKW);    // 2,097,152 bf16
  ushort_t* xb = (ushort_t*)(qkvfull + (size_t)B_ * T_ * NQKV);   // 8,388,608 bf16
  ushort_t* wt = xb + (size_t)B_ * T_ * KS2;                      // 3,670,016 bf16
  ushort_t* wpf = wt + (size_t)NQKV * KS2;                        //   131,072 bf16
  ushort_t* qf = xb;                                              // 4,194,304 bf16
  ushort_t* kf = qf + (size_t)B_ * H_ * T_ * 64;                  // 1,048,576 bf16
  float* y = (float*)(kf + (size_t)B_ * G_ * T_ * 64);            //   524,288 f32

  // 5 dispatches: prep -> gemm(+vscatter) -> rope(+y-zero) -> attn -> out_proj
  prep<<<2560, 256, 0, stream>>>(x, Wq, Wk, Wv, Wproj, xb, wt, wpf);

  dim3 gg(NQKV / 128, (B_ * T_) / 128);
  gemm_qkv_mfma<<<gg, 256, 0, stream>>>(xb, wt, qkv, vf);

  rope_scatter<<<20992, 256, 0, stream>>>(qkv, qf, kf, y);

  attn<<<B_ * H_ * 32, 256, 0, stream>>>(qf, kf, vf, lobo, qknf, y);

  dim3 go(8, 32);
  out_proj<<<go, 256, 0, stream>>>(y, wpf, out);
}

// Round 15
// 195.875 us; speedup vs baseline: 1.2435x; 1.0949x over previous
//
#include <hip/hip_runtime.h>
#include <hip/hip_bf16.h>
#include <math.h>

#define B_ 2
#define T_ 2048
#define C_ 1024
#define H_ 16
#define G_ 4
#define DQK_ 64
#define DV_ 128
#define NQKV 1792   // H*DQK + G*DQK + G*DV
#define KS2 2048    // compact split storage: [hi | lo]
// Variable-K split GEMM: Q/K columns (n<1280) use 2048 K-depth
// (hi·hi + lo·hi); V columns (n>=1280) use 1024 (hi·hi only).
// Operand rows chunk-XOR-swizzled: chunk c of row r at phys chunk c^((r>>1)&3).

typedef __attribute__((ext_vector_type(8))) short short8;
typedef __attribute__((ext_vector_type(4))) float f32x4;
typedef unsigned short ushort_t;

__device__ inline ushort_t f2bf(float f) {
  union { float f; unsigned int u; } v; v.f = f;
  unsigned int r = (v.u + 0x7FFFu + ((v.u >> 16) & 1u)) >> 16;  // RNE
  return (ushort_t)r;
}
__device__ inline float bf2f(ushort_t h) {
  union { unsigned int u; float f; } v; v.u = ((unsigned int)h) << 16;
  return v.f;
}
// single-instruction RNE f32->bf16 (dst.lo = cvt(src)); P is finite in (0,1]
__device__ inline ushort_t f2bf_hw(float f) {
  unsigned int u;
  asm("v_cvt_pk_bf16_f32 %0, %1, %1" : "=v"(u) : "v"(f));
  return (ushort_t)u;
}

#define GLD_LDS16(g, l)                                              \
  __builtin_amdgcn_global_load_lds(                                  \
      (const __attribute__((address_space(1))) void*)(g),            \
      (__attribute__((address_space(3))) void*)(l), 16, 0, 0)

// ---------------------------------------------------------------------------
// Kernel 0 (FUSED): prep = cast_x | cast_w | cast_wp | y-zero by range.
// ---------------------------------------------------------------------------
__global__ __launch_bounds__(256) void prep(
    const float* __restrict__ x, const float* __restrict__ Wq,
    const float* __restrict__ Wk, const float* __restrict__ Wv,
    const float* __restrict__ Wproj, ushort_t* __restrict__ xb,
    ushort_t* __restrict__ wt, ushort_t* __restrict__ wpf,
    float* __restrict__ y) {
  __shared__ float tile[64][65];
  const int bid = blockIdx.x;
  const int tid = threadIdx.x;

  if (bid < 2048) {
    // ---- cast_x ----
    int idx = bid * 256 + tid;   // 524288
    int m = idx >> 7;
    int c8 = idx & 127;
    const float* src = &x[(size_t)m * 1024 + c8 * 8];
    float4 v0 = *(const float4*)&src[0];
    float4 v1 = *(const float4*)&src[4];
    float f[8] = {v0.x, v0.y, v0.z, v0.w, v1.x, v1.y, v1.z, v1.w};
    short8 hv, lv;
#pragma unroll
    for (int c = 0; c < 8; c++) {
      ushort_t h = f2bf(f[c]);
      hv[c] = (short)h;
      lv[c] = (short)f2bf(f[c] - bf2f(h));
    }
    int key = (m >> 1) & 3;
    int phys = (c8 & ~3) * 8 + ((c8 & 3) ^ key) * 8;
    ushort_t* row = xb + (size_t)m * KS2;
    *(short8*)&row[phys] = hv;
    *(short8*)&row[1024 + phys] = lv;
  } else if (bid < 2496) {
    // ---- cast_w ----
    const int wid = bid - 2048;          // 0..447 = 28 x 16
    const int n0 = (wid % 28) * 64;
    const int k0 = (wid / 28) * 64;

    const float* Wp; int ldw, noff;
    if (n0 < 1024)      { Wp = Wq; ldw = 1024; noff = n0; }
    else if (n0 < 1280) { Wp = Wk; ldw = 256;  noff = n0 - 1024; }
    else                { Wp = Wv; ldw = 512;  noff = n0 - 1280; }

#pragma unroll
    for (int it = 0; it < 4; it++) {
      int fi = it * 256 + tid;
      int kk = fi >> 4;
      int nc = (fi & 15) * 4;
      float4 v = *(const float4*)&Wp[(size_t)(k0 + kk) * ldw + noff + nc];
      tile[nc + 0][kk] = v.x; tile[nc + 1][kk] = v.y;
      tile[nc + 2][kk] = v.z; tile[nc + 3][kk] = v.w;
    }
    __syncthreads();
    int nn = tid >> 2, seg = tid & 3;
    int n = n0 + nn;
    int key = (n >> 1) & 3;
    ushort_t* row = wt + (size_t)n * KS2;
#pragma unroll
    for (int j = 0; j < 2; j++) {
      short8 hv;
#pragma unroll
      for (int u = 0; u < 8; u++)
        hv[u] = (short)f2bf(tile[nn][seg * 16 + j * 8 + u]);
      int c8 = (k0 >> 3) + seg * 2 + j;
      int phys = (c8 & ~3) * 8 + ((c8 & 3) ^ key) * 8;
      *(short8*)&row[phys] = hv;
    }
  } else if (bid < 2560) {
    // ---- cast_wp ----
    int idx = (bid - 2496) * 256 + tid;  // 16384
    int n = idx & 1023;
    int kc = idx >> 10;                  // 0..15 (chunk of 8 k's)
    short8 v;
#pragma unroll
    for (int j = 0; j < 8; j++)
      v[j] = (short)f2bf(Wproj[(size_t)(kc * 8 + j) * 1024 + n]);
    size_t off = (((size_t)(n >> 7) * 4 + (kc >> 2)) * 8 + ((n >> 4) & 7)) * 512 +
                 ((kc & 3) * 16 + (n & 15)) * 8;
    *(short8*)&wpf[off] = v;
  } else {
    // ---- zero y (y no longer aliases xb, safe to zero here) ----
    int idx = (bid - 2560) * 256 + tid;   // 131072 float4s
    *(float4*)&y[(size_t)idx * 4] = (float4){0.f, 0.f, 0.f, 0.f};
  }
}

// ---------------------------------------------------------------------------
// Kernel 1: bf16-MFMA QKV GEMM, BK=64.
// ROUND 15: FULLY FUSED EPILOGUE — qkv f32 intermediate ELIMINATED.
//  - V-cols (n0>=1280): bf16 cast + PV B-fragment store to vf (r14 proven).
//  - Q/K-cols: RoPE + qk-norm + bf16 fragment store to qf/kf, in-register:
//     * wave owns 64 rows x 64 cols = one full head per row (wn 64-aligned);
//     * partner dim d^32 = 16*(j^2)+l16 -> SAME lane, register acc[i][j^2][r];
//     * row-norm: sum 4 regs + shfl_xor masks 1,2,4,8 (16-lane quad group
//       holds the same row);
//     * store mapping == rope_norm's: ks=j>>1, qd=(2j+(l16>>3))&3, jj=l16&7,
//       Q idx512 = (t>>6)*8+((t&63)>>4)*2+ks, K idx512 = (t>>6)*8+ks*4+((t&63)>>4).
//  - Saves 21MB qkv write + 21MB read + the rope dispatch + its launch gap.
//  - Alias audit: gemm reads {xb,wt}, writes {qf,kf,vf} — all disjoint
//    (qf/kf/vf/y moved into the freed old-qkv region; xb untouched).
// ---------------------------------------------------------------------------
__global__ __launch_bounds__(256) void gemm_qkv_mfma(
    const ushort_t* __restrict__ xb, const ushort_t* __restrict__ wt,
    ushort_t* __restrict__ qf, ushort_t* __restrict__ kf,
    ushort_t* __restrict__ vf) {
  __shared__ ushort_t At[128 * 64];
  __shared__ ushort_t Bt[128 * 64];
  const int tid = threadIdx.x;
  const int wave = tid >> 6, lane = tid & 63;
  const int quad = lane >> 4, l16 = lane & 15;
  const int m0 = blockIdx.y * 128, n0 = blockIdx.x * 128;
  const int wm = (wave & 1) * 64, wn = (wave >> 1) * 64;
  const int key = (l16 >> 1) & 3;
  const int ntiles = (n0 >= 1280) ? 16 : 32;

  f32x4 acc[4][4];
#pragma unroll
  for (int i = 0; i < 4; i++)
#pragma unroll
    for (int j = 0; j < 4; j++) acc[i][j] = (f32x4){0.f, 0.f, 0.f, 0.f};

  const int rA = wave * 32 + (lane >> 3);
  const int cA = (lane & 7) * 8;
  const ushort_t* gA = xb + (size_t)(m0 + rA) * KS2 + cA;
  const ushort_t* gB = wt + (size_t)(n0 + rA) * KS2 + cA;

  for (int kt = 0; kt < ntiles; kt++) {
    const int ca = kt * 64;                         // A walks hi then lo
    const int cb = (kt < 16 ? kt : kt - 16) * 64;   // B wraps within hi
    __syncthreads();
#pragma unroll
    for (int j = 0; j < 4; j++) {
      GLD_LDS16(gA + ca + (size_t)(8 * j) * KS2, &At[(wave * 32 + 8 * j) * 64]);
      GLD_LDS16(gB + cb + (size_t)(8 * j) * KS2, &Bt[(wave * 32 + 8 * j) * 64]);
    }
    __syncthreads();

#pragma unroll
    for (int s = 0; s < 2; s++) {
      const int off = s * 32 + ((quad ^ key) * 8);
      short8 af[4], bf[4];
#pragma unroll
      for (int i = 0; i < 4; i++)
        af[i] = *(const short8*)&At[(wm + 16 * i + l16) * 64 + off];
#pragma unroll
      for (int j = 0; j < 4; j++)
        bf[j] = *(const short8*)&Bt[(wn + 16 * j + l16) * 64 + off];
#pragma unroll
      for (int i = 0; i < 4; i++)
#pragma unroll
        for (int j = 0; j < 4; j++)
          acc[i][j] = __builtin_amdgcn_mfma_f32_16x16x32_bf16(
              af[i], bf[j], acc[i][j], 0, 0, 0);
    }
  }

  const int b = m0 >> 11;   // whole block shares one batch (128 | 2048)

  if (n0 >= 1280) {
    // ---- fused vscatter: bf16 cast + PV B-fragment layout store ----
    const int g = (n0 - 1280) >> 7;
    ushort_t* vg = vf + (size_t)(b * 4 + g) * 262144;
#pragma unroll
    for (int i = 0; i < 4; i++) {
      int mbase = m0 + wm + 16 * i + quad * 4;
#pragma unroll
      for (int jn = 0; jn < 4; jn++) {
        int nv = (wn >> 4) + jn;
#pragma unroll
        for (int r = 0; r < 4; r++) {
          int t = (mbase + r) & 2047;
          int tk = t >> 6, ks = (t >> 5) & 1, qd = (t >> 3) & 3, jj = t & 7;
          size_t off = ((size_t)(tk * 16 + ks * 8 + nv) * 4 + qd) * 128 +
                       l16 * 8 + jj;
          vg[off] = f2bf(acc[i][jn][r]);
        }
      }
    }
  } else {
    // ---- fused RoPE + qk-norm + fragment store ----
    const int headn = n0 + wn;            // 64-aligned: one head per wave
    const bool isq = headn < 1024;
    ushort_t* dstbase = isq
        ? qf + (size_t)(b * 16 + (headn >> 6)) * 131072
        : kf + (size_t)(b * 4 + ((headn - 1024) >> 6)) * 131072;
    const float c0 = 0.4152410118074239f;          // log2(10000)/32
    const float inv_lo = exp2f(-(float)l16 * c0);
    const float inv_hi = exp2f(-(float)(16 + l16) * c0);
    const int jj = l16 & 7;

#pragma unroll
    for (int i = 0; i < 4; i++) {
#pragma unroll
      for (int r = 0; r < 4; r++) {
        int t = (m0 + wm + 16 * i + quad * 4 + r) & 2047;
        float sn0, cs0, sn1, cs1;
        __sincosf((float)t * inv_lo, &sn0, &cs0);
        __sincosf((float)t * inv_hi, &sn1, &cs1);
        // d = 16*j + l16; partner d^32 -> register j^2 (same lane)
        float rv0 = acc[i][0][r] * cs0 - acc[i][2][r] * sn0;   // d in [0,16)
        float rv1 = acc[i][1][r] * cs1 - acc[i][3][r] * sn1;   // d in [16,32)
        float rv2 = acc[i][2][r] * cs0 + acc[i][0][r] * sn0;   // d in [32,48)
        float rv3 = acc[i][3][r] * cs1 + acc[i][1][r] * sn1;   // d in [48,64)
        float ss = rv0 * rv0 + rv1 * rv1 + rv2 * rv2 + rv3 * rv3;
        ss += __shfl_xor(ss, 1, 64);
        ss += __shfl_xor(ss, 2, 64);
        ss += __shfl_xor(ss, 4, 64);
        ss += __shfl_xor(ss, 8, 64);
        float sc = 1.0f / (sqrtf(ss) + 1e-6f);
        int kt8 = t >> 6, tt = t & 63;
        int l16v = tt & 15, nt = tt >> 4;
        float rv[4] = {rv0, rv1, rv2, rv3};
#pragma unroll
        for (int j = 0; j < 4; j++) {
          int ks = j >> 1;
          int qd = (2 * j + (l16 >> 3)) & 3;
          size_t idx512 = isq ? (size_t)(kt8 * 8 + nt * 2 + ks)
                              : (size_t)(kt8 * 8 + ks * 4 + nt);
          dstbase[idx512 * 512 + qd * 128 + l16v * 8 + jj] = f2bf(rv[j] * sc);
        }
      }
    }
  }
}

// ---------------------------------------------------------------------------
// Kernel 3: bf16-MFMA causal flash attention (ROUND-10 BODY — best passing:
// 65.6us).  Single-buffer K/V LDS staging (2 barriers wrap staging only),
// 4 blocks/CU declared, serpentine balanced slot map, v_cvt_pk f2bf + fma
// exp arg.
// ---------------------------------------------------------------------------
__global__ __launch_bounds__(256, 4) void attn(
    const ushort_t* __restrict__ qf, const ushort_t* __restrict__ kf,
    const ushort_t* __restrict__ vf, const float* __restrict__ lobo,
    const float* __restrict__ qknf, float* __restrict__ y) {
  const int f = blockIdx.x;            // 1024 blocks
  const int bh = f & 31;
  const int slot = f >> 5;             // 0..31
  int tq;
  if (slot < 8)       tq = 31 - slot;  // 31..24
  else if (slot < 16) tq = 8 + slot;   // 16..23
  else if (slot < 24) tq = 31 - slot;  // 15..8
  else                tq = slot - 24;  // 0..7
  const int b = bh >> 4;
  const int h = bh & 15;
  const int g = h >> 2;

  __shared__ ushort_t KV[12288];       // [K: 8 x 512 | V: 16 x 512] per kt
  __shared__ ushort_t Ps[4 * 1088];    // per-wave 16 rows x 68

  const int tid = threadIdx.x;
  const int wave = tid >> 6, lane = tid & 63;
  const int quad = lane >> 4, l16 = lane & 15;
  ushort_t* PsW = &Ps[wave * 1088];

  short8 bones;
  {
    short bv = (l16 == 0) ? (short)0x3F80 : (short)0;
#pragma unroll
    for (int j = 0; j < 8; j++) bones[j] = bv;
  }

  const ushort_t* qbase = qf + (size_t)(b * 16 + h) * 131072 + lane * 8;
  short8 aq0 = *(const short8*)&qbase[(size_t)(tq * 8 + wave * 2 + 0) * 512];
  short8 aq1 = *(const short8*)&qbase[(size_t)(tq * 8 + wave * 2 + 1) * 512];

  f32x4 o[9];
#pragma unroll
  for (int nv = 0; nv < 9; nv++) o[nv] = (f32x4){0.f, 0.f, 0.f, 0.f};

  const float gsc = qknf[0];
  const float sinkp = __expf(lobo[h] - gsc);

  const int row = tq * 64 + wave * 16 + quad * 4;   // +r

  // per-lane global pointers for staging (lane*8 element offset built in)
  const ushort_t* kgl = kf + (size_t)(b * 4 + g) * 131072 + lane * 8;
  const ushort_t* vgl = vf + (size_t)(b * 4 + g) * 262144 + lane * 8;

  for (int kt = 0; kt <= tq; kt++) {
    // ---- stage K+V tile into LDS (barriers wrap staging ONLY) ----
    __syncthreads();   // previous iteration's KV reads complete
    {
      const ushort_t* gk = kgl + (size_t)kt * 4096;
      const ushort_t* gv = vgl + (size_t)kt * 8192;
      GLD_LDS16(gk + (wave * 2 + 0) * 512, &KV[(wave * 2 + 0) * 512]);
      GLD_LDS16(gk + (wave * 2 + 1) * 512, &KV[(wave * 2 + 1) * 512]);
#pragma unroll
      for (int j = 0; j < 4; j++)
        GLD_LDS16(gv + (wave * 4 + j) * 512, &KV[4096 + (wave * 4 + j) * 512]);
    }
    __syncthreads();   // staging complete (implicit vmcnt drain)

    // ---- QK: K frags from LDS in two batches of 4 ----
    f32x4 s[4];
#pragma unroll
    for (int nt = 0; nt < 4; nt++) s[nt] = (f32x4){0.f, 0.f, 0.f, 0.f};
    {
      short8 kb[4];
#pragma unroll
      for (int u = 0; u < 4; u++)
        kb[u] = *(const short8*)&KV[u * 512 + lane * 8];
      __builtin_amdgcn_s_setprio(1);
#pragma unroll
      for (int nt = 0; nt < 4; nt++)
        s[nt] = __builtin_amdgcn_mfma_f32_16x16x32_bf16(aq0, kb[nt], s[nt], 0, 0, 0);
      __builtin_amdgcn_s_setprio(0);
#pragma unroll
      for (int u = 0; u < 4; u++)
        kb[u] = *(const short8*)&KV[(4 + u) * 512 + lane * 8];
      __builtin_amdgcn_s_setprio(1);
#pragma unroll
      for (int nt = 0; nt < 4; nt++)
        s[nt] = __builtin_amdgcn_mfma_f32_16x16x32_bf16(aq1, kb[nt], s[nt], 0, 0, 0);
      __builtin_amdgcn_s_setprio(0);
    }

    // ---- mask + exp + bf16 store; causal cmp only on diagonal iter ----
    if (kt == tq) {
#pragma unroll
      for (int nt = 0; nt < 4; nt++) {
        int key = kt * 64 + l16 + nt * 16;
#pragma unroll
        for (int r = 0; r < 4; r++) {
          float pv = (key <= row + r) ? __expf(fmaf(s[nt][r], gsc, -gsc)) : 0.f;
          PsW[(quad * 4 + r) * 68 + nt * 16 + l16] = f2bf_hw(pv);
        }
      }
    } else {
#pragma unroll
      for (int nt = 0; nt < 4; nt++)
#pragma unroll
        for (int r = 0; r < 4; r++)
          PsW[(quad * 4 + r) * 68 + nt * 16 + l16] =
              f2bf_hw(__expf(fmaf(s[nt][r], gsc, -gsc)));
    }

    // ---- read P fragments, PV with V frags from LDS (4 batches of 4) ----
    short8 ap0 = *(const short8*)&PsW[l16 * 68 + quad * 8];
    short8 ap1 = *(const short8*)&PsW[l16 * 68 + 32 + quad * 8];
    {
      short8 vb[4];
#pragma unroll
      for (int u = 0; u < 4; u++)
        vb[u] = *(const short8*)&KV[4096 + u * 512 + lane * 8];
      __builtin_amdgcn_s_setprio(1);
#pragma unroll
      for (int nv = 0; nv < 4; nv++)
        o[nv] = __builtin_amdgcn_mfma_f32_16x16x32_bf16(ap0, vb[nv], o[nv], 0, 0, 0);
      __builtin_amdgcn_s_setprio(0);
#pragma unroll
      for (int u = 0; u < 4; u++)
        vb[u] = *(const short8*)&KV[4096 + (4 + u) * 512 + lane * 8];
      __builtin_amdgcn_s_setprio(1);
#pragma unroll
      for (int nv = 0; nv < 4; nv++)
        o[4 + nv] = __builtin_amdgcn_mfma_f32_16x16x32_bf16(ap0, vb[nv], o[4 + nv], 0, 0, 0);
      o[8] = __builtin_amdgcn_mfma_f32_16x16x32_bf16(ap0, bones, o[8], 0, 0, 0);
      o[8] = __builtin_amdgcn_mfma_f32_16x16x32_bf16(ap1, bones, o[8], 0, 0, 0);
      __builtin_amdgcn_s_setprio(0);
#pragma unroll
      for (int u = 0; u < 4; u++)
        vb[u] = *(const short8*)&KV[4096 + (8 + u) * 512 + lane * 8];
      __builtin_amdgcn_s_setprio(1);
#pragma unroll
      for (int nv = 0; nv < 4; nv++)
        o[nv] = __builtin_amdgcn_mfma_f32_16x16x32_bf16(ap1, vb[nv], o[nv], 0, 0, 0);
      __builtin_amdgcn_s_setprio(0);
#pragma unroll
      for (int u = 0; u < 4; u++)
        vb[u] = *(const short8*)&KV[4096 + (12 + u) * 512 + lane * 8];
      __builtin_amdgcn_s_setprio(1);
#pragma unroll
      for (int nv = 0; nv < 4; nv++)
        o[4 + nv] = __builtin_amdgcn_mfma_f32_16x16x32_bf16(ap1, vb[nv], o[4 + nv], 0, 0, 0);
      __builtin_amdgcn_s_setprio(0);
    }
  }

  // epilogue: l = sink + mfma row-sum (col 0 of o[8]); normalize; head-sum
#pragma unroll
  for (int r = 0; r < 4; r++) {
    float lm = __shfl(o[8][r], lane & 48, 64);
    float invl = 1.0f / (lm + sinkp);
    size_t gRow = (size_t)b * T_ + row + r;
#pragma unroll
    for (int nv = 0; nv < 8; nv++)
      atomicAdd(&y[gRow * 128 + nv * 16 + l16], o[nv][r] * invl);
  }
}

// ---------------------------------------------------------------------------
// Kernel 4: out = y[4096][128] @ Wproj[128][1024] via bf16 MFMA.
// ---------------------------------------------------------------------------
__global__ __launch_bounds__(256) void out_proj(
    const float* __restrict__ y, const ushort_t* __restrict__ wpf,
    float* __restrict__ out) {
  __shared__ ushort_t yl[128 * 136];
  const int tid = threadIdx.x;
  const int wave = tid >> 6, lane = tid & 63;
  const int quad = lane >> 4, l16 = lane & 15;
  const int n0 = blockIdx.x * 128, m0 = blockIdx.y * 128;
  const int wm = (wave & 1) * 64, wn = (wave >> 1) * 64;

#pragma unroll
  for (int it = 0; it < 8; it++) {
    int p = it * 256 + tid;
    int row = p >> 4, c8 = p & 15;
    const float* src = &y[(size_t)(m0 + row) * 128 + c8 * 8];
    float4 v0 = *(const float4*)&src[0];
    float4 v1 = *(const float4*)&src[4];
    float fv[8] = {v0.x, v0.y, v0.z, v0.w, v1.x, v1.y, v1.z, v1.w};
    short8 hv;
#pragma unroll
    for (int c = 0; c < 8; c++) hv[c] = (short)f2bf(fv[c]);
    *(short8*)&yl[row * 136 + c8 * 8] = hv;
  }
  __syncthreads();

  f32x4 acc[4][4];
#pragma unroll
  for (int i = 0; i < 4; i++)
#pragma unroll
    for (int j = 0; j < 4; j++) acc[i][j] = (f32x4){0.f, 0.f, 0.f, 0.f};

#pragma unroll
  for (int ks = 0; ks < 4; ks++) {
    short8 af[4], bfr[4];
#pragma unroll
    for (int i = 0; i < 4; i++)
      af[i] = *(const short8*)&yl[(wm + 16 * i + l16) * 136 + (ks * 4 + quad) * 8];
    const ushort_t* wb = wpf + (((size_t)(n0 >> 7) * 4 + ks) * 8) * 512;
#pragma unroll
    for (int j = 0; j < 4; j++)
      bfr[j] = *(const short8*)&wb[((size_t)((wn >> 4) + j)) * 512 + lane * 8];
#pragma unroll
    for (int i = 0; i < 4; i++)
#pragma unroll
      for (int j = 0; j < 4; j++)
        acc[i][j] = __builtin_amdgcn_mfma_f32_16x16x32_bf16(
            af[i], bfr[j], acc[i][j], 0, 0, 0);
  }

#pragma unroll
  for (int i = 0; i < 4; i++) {
    int m = m0 + wm + 16 * i + quad * 4;
#pragma unroll
    for (int j = 0; j < 4; j++) {
      int n = n0 + wn + 16 * j + l16;
#pragma unroll
      for (int r = 0; r < 4; r++)
        out[(size_t)(m + r) * 1024 + n] = acc[i][j][r];
    }
  }
}

// ---------------------------------------------------------------------------
extern "C" void kernel_launch(void* const* d_in, const int* in_sizes, int n_in,
                              void* d_out, int out_size, void* d_ws, size_t ws_size,
                              hipStream_t stream) {
  const float* x     = (const float*)d_in[0];
  const float* Wq    = (const float*)d_in[2];
  const float* Wk    = (const float*)d_in[3];
  const float* Wv    = (const float*)d_in[4];
  const float* Wproj = (const float*)d_in[5];
  const float* lobo  = (const float*)d_in[6];
  const float* qknf  = (const float*)d_in[7];
  float* out = (float*)d_out;

  // ws layout (footprint unchanged; qkv f32 intermediate ELIMINATED):
  //  [0, 8.39MB)    qf bf16 (4,194,304) — written by gemm, read by attn
  //  [8.39, 10.49)  kf bf16 (1,048,576)
  //  [10.49, 14.68) vf bf16 (2,097,152)
  //  [14.68, 16.78) y  f32  (524,288) — zeroed by prep, atomics by attn
  //  [29.36, 46.14) xb bf16 (8,388,608) — written by prep, read by gemm
  //  [46.14, 53.48) wt bf16;  [53.48, 53.74) wpf bf16
  //  All producer->consumer pairs disjoint: no intra-kernel aliases.
  ushort_t* qf = (ushort_t*)d_ws;                                 // 4,194,304
  ushort_t* kf = qf + (size_t)B_ * H_ * T_ * 64;                  // 1,048,576
  ushort_t* vf = kf + (size_t)B_ * G_ * T_ * 64;                  // 2,097,152
  float* y = (float*)(vf + (size_t)B_ * G_ * T_ * 128);           //   524,288 f32
  ushort_t* xb = (ushort_t*)((float*)d_ws + (size_t)B_ * T_ * NQKV);  // 8,388,608
  ushort_t* wt = xb + (size_t)B_ * T_ * KS2;                      // 3,670,016
  ushort_t* wpf = wt + (size_t)NQKV * KS2;                        //   131,072

  // 4 dispatches: prep(+y-zero) -> gemm(+rope+vscatter) -> attn -> out_proj
  prep<<<3072, 256, 0, stream>>>(x, Wq, Wk, Wv, Wproj, xb, wt, wpf, y);

  dim3 gg(NQKV / 128, (B_ * T_) / 128);
  gemm_qkv_mfma<<<gg, 256, 0, stream>>>(xb, wt, qf, kf, vf);

  attn<<<B_ * H_ * 32, 256, 0, stream>>>(qf, kf, vf, lobo, qknf, y);

  dim3 go(8, 32);
  out_proj<<<go, 256, 0, stream>>>(y, wpf, out);
}